// Round 10
// baseline (341.283 us; speedup 1.0000x reference)
//
#include <hip/hip_runtime.h>

typedef float v2f __attribute__((ext_vector_type(2)));

// Problem constants
constexpr int BB = 2;        // batch
constexpr int CM = 96;       // d_model
constexpr int CI = 192;      // d_inner
constexpr int NPIX = 128 * 128;   // 16384
constexpr int DS = 16;            // d_state
constexpr int DC = 4 * CI;        // 768

// workspace layout (floats). Overlays:
//   ypB <- x1pre (dead after K2);  ym <- x1T (dead after K4);
//   mu/rstd <- xp (dead after K4); yt <- x1 (dead after K4).
constexpr size_t OFF_X1PRE = 0;
constexpr size_t OFF_X1    = 6291456;
constexpr size_t OFF_X1T   = 12582912;
constexpr size_t OFF_XP    = 18874368;
constexpr size_t OFF_YPA   = 19398656;
constexpr size_t OFF_YPB   = 0;          // alias x1pre
constexpr size_t OFF_YM    = 12582912;   // alias x1T
constexpr size_t OFF_MU    = 18874368;   // alias xp (first 32768)
constexpr size_t OFF_RSTD  = 18874368 + 32768;
constexpr size_t OFF_YT    = 6291456;    // alias x1
constexpr size_t OFF_GXS   = 25690112;

__device__ __forceinline__ float frcp(float x) { return __builtin_amdgcn_rcpf(x); }
// DPP whole-wave shifts: from_lower = lane n reads lane n-1 (lane0 -> 0),
// from_upper = lane n reads lane n+1 (lane63 -> 0). old=0 fallback.
__device__ __forceinline__ float dpp_from_lower(float x) {
    return __int_as_float(__builtin_amdgcn_update_dpp(
        0, __float_as_int(x), 0x138, 0xf, 0xf, false));   // wave_shr1
}
__device__ __forceinline__ float dpp_from_upper(float x) {
    return __int_as_float(__builtin_amdgcn_update_dpp(
        0, __float_as_int(x), 0x130, 0xf, 0xf, false));   // wave_shl1
}
__device__ __forceinline__ float rdlane(float x, int lane) {
    return __int_as_float(__builtin_amdgcn_readlane(__float_as_int(x), lane));
}

// ---------------------------------------------------------------------------
// K1: x1_pre = conv1x1(x, w_in)   (B,96,H,W) -> (B,192,H,W)
__global__ __launch_bounds__(256) void k1_conv_in(const float* __restrict__ x,
                                                  const float* __restrict__ w_in,
                                                  float* __restrict__ x1pre) {
    __shared__ float xs[16][128];
    __shared__ float wsh[16][32];
    int pt = blockIdx.x;
    int b = pt >> 7;
    int pxb = (pt & 127) * 128;
    int cb = blockIdx.y * 32;
    int tid = threadIdx.x;
    int cl0 = (tid >> 5) * 4;
    int px0 = (tid & 31) * 4;
    float acc[4][4];
#pragma unroll
    for (int i = 0; i < 4; i++)
#pragma unroll
        for (int j = 0; j < 4; j++) acc[i][j] = 0.f;

    for (int m0 = 0; m0 < 96; m0 += 16) {
        {
            int e = tid * 8;
            int ml = e >> 7, pp = e & 127;
            const float* src = &x[((size_t)(b * CM + m0 + ml)) * NPIX + pxb + pp];
            float4 v0 = *(const float4*)(src);
            float4 v1 = *(const float4*)(src + 4);
            *(float4*)&xs[ml][pp] = v0;
            *(float4*)&xs[ml][pp + 4] = v1;
        }
        if (tid < 128) {
            int cl = tid >> 2, mq = (tid & 3) * 4;
            float4 v = *(const float4*)&w_in[(size_t)(cb + cl) * CM + m0 + mq];
            wsh[mq + 0][cl] = v.x; wsh[mq + 1][cl] = v.y;
            wsh[mq + 2][cl] = v.z; wsh[mq + 3][cl] = v.w;
        }
        __syncthreads();
#pragma unroll
        for (int m = 0; m < 16; m++) {
            float4 wv = *(const float4*)&wsh[m][cl0];
            float4 xv = *(const float4*)&xs[m][px0];
            float wr[4] = {wv.x, wv.y, wv.z, wv.w};
            float xr[4] = {xv.x, xv.y, xv.z, xv.w};
#pragma unroll
            for (int i = 0; i < 4; i++)
#pragma unroll
                for (int j = 0; j < 4; j++) acc[i][j] += wr[i] * xr[j];
        }
        __syncthreads();
    }
#pragma unroll
    for (int i = 0; i < 4; i++) {
        float4 v = {acc[i][0], acc[i][1], acc[i][2], acc[i][3]};
        *(float4*)&x1pre[((size_t)(b * CI + cb + cl0 + i)) * NPIX + pxb + px0] = v;
    }
}

// ---------------------------------------------------------------------------
// K2: x1 = dwconv3x3(x1_pre)+b, writes BOTH x1 [h][w] and x1T [w][h].
__global__ __launch_bounds__(256) void k2_dwconv(const float* __restrict__ x1pre,
                                                 const float* __restrict__ w_dw,
                                                 const float* __restrict__ b_dw,
                                                 float* __restrict__ x1,
                                                 float* __restrict__ x1T) {
    __shared__ float inT[66][67];
    __shared__ float outT[64][65];
    int blk = blockIdx.x;
    int bc = blk >> 2;
    int tile = blk & 3;
    int h0 = (tile >> 1) * 64, w0 = (tile & 1) * 64;
    int c = bc % CI;
    const float* src = x1pre + (size_t)bc * NPIX;
    int tid = threadIdx.x;
    for (int idx = tid; idx < 66 * 66; idx += 256) {
        int r = idx / 66, cl = idx - r * 66;
        int hh = h0 - 1 + r, ww = w0 - 1 + cl;
        float v = 0.f;
        if ((unsigned)hh < 128u && (unsigned)ww < 128u) v = src[hh * 128 + ww];
        inT[r][cl] = v;
    }
    float w00 = w_dw[c * 9 + 0], w01 = w_dw[c * 9 + 1], w02 = w_dw[c * 9 + 2];
    float w10 = w_dw[c * 9 + 3], w11 = w_dw[c * 9 + 4], w12 = w_dw[c * 9 + 5];
    float w20 = w_dw[c * 9 + 6], w21 = w_dw[c * 9 + 7], w22 = w_dw[c * 9 + 8];
    float bias = b_dw[c];
    __syncthreads();
    int cl = tid & 63, r0 = tid >> 6;
#pragma unroll 4
    for (int k = 0; k < 16; k++) {
        int r = k * 4 + r0;
        float s = w00 * inT[r][cl]     + w01 * inT[r][cl + 1]     + w02 * inT[r][cl + 2]
                + w10 * inT[r + 1][cl] + w11 * inT[r + 1][cl + 1] + w12 * inT[r + 1][cl + 2]
                + w20 * inT[r + 2][cl] + w21 * inT[r + 2][cl + 1] + w22 * inT[r + 2][cl + 2]
                + bias;
        x1[(size_t)bc * NPIX + (h0 + r) * 128 + w0 + cl] = s;
        outT[r][cl] = s;
    }
    __syncthreads();
#pragma unroll 4
    for (int k = 0; k < 16; k++) {
        int r = k * 4 + r0;
        x1T[(size_t)bc * NPIX + (w0 + r) * 128 + h0 + cl] = outT[cl][r];
    }
}

// ---------------------------------------------------------------------------
// K3: xp = conv1x1(x1, w_xdown) via x1T, stored (b, w, h, 16).
// grid = B*128(w)*4(h-quarter); 256 thr = 32 px x 8 c-groups(24).
__global__ __launch_bounds__(256) void k3_xp(const float* __restrict__ x1T,
                                             const float* __restrict__ w_xdown,
                                             float* __restrict__ xp) {
    __shared__ float wsh_t[CI * DS];        // [c][s] transposed, 12 KB
    __shared__ float red[8][32][20];        // padded, 20.5 KB
    int blk = blockIdx.x;
    int b = blk >> 9;
    int rest = blk & 511;
    int t = rest >> 2;                      // w index
    int hq = rest & 3;
    int tid = threadIdx.x;
#pragma unroll
    for (int rep = 0; rep < 12; rep++) {
        int e = rep * 256 + tid;            // e = s*CI + c
        int s = e / CI;
        int cc = e - s * CI;
        wsh_t[cc * DS + s] = w_xdown[e];
    }
    int pl = tid & 31;                      // px within quarter
    int cg = tid >> 5;                      // 8 groups
    int c0 = cg * 24;
    int hpix = hq * 32 + pl;
    __syncthreads();
    float acc[DS];
#pragma unroll
    for (int s = 0; s < DS; s++) acc[s] = 0.f;
    const float* xb = x1T + ((size_t)b * CI + c0) * NPIX + t * 128 + hpix;
#pragma unroll 4
    for (int cc = 0; cc < 24; cc++) {
        float v = xb[(size_t)cc * NPIX];
        const float4* wr4 = (const float4*)&wsh_t[(c0 + cc) * DS];
        float4 w0 = wr4[0], w1 = wr4[1], w2 = wr4[2], w3 = wr4[3];
        acc[0] = fmaf(w0.x, v, acc[0]);  acc[1] = fmaf(w0.y, v, acc[1]);
        acc[2] = fmaf(w0.z, v, acc[2]);  acc[3] = fmaf(w0.w, v, acc[3]);
        acc[4] = fmaf(w1.x, v, acc[4]);  acc[5] = fmaf(w1.y, v, acc[5]);
        acc[6] = fmaf(w1.z, v, acc[6]);  acc[7] = fmaf(w1.w, v, acc[7]);
        acc[8] = fmaf(w2.x, v, acc[8]);  acc[9] = fmaf(w2.y, v, acc[9]);
        acc[10] = fmaf(w2.z, v, acc[10]); acc[11] = fmaf(w2.w, v, acc[11]);
        acc[12] = fmaf(w3.x, v, acc[12]); acc[13] = fmaf(w3.y, v, acc[13]);
        acc[14] = fmaf(w3.z, v, acc[14]); acc[15] = fmaf(w3.w, v, acc[15]);
    }
#pragma unroll
    for (int q = 0; q < 4; q++)
        *(float4*)&red[cg][pl][q * 4] = *(float4*)&acc[q * 4];
    __syncthreads();
    int px = tid >> 3;
    int s2 = (tid & 7) * 2;
    float r0 = 0.f, r1 = 0.f;
#pragma unroll
    for (int g = 0; g < 8; g++) { r0 += red[g][px][s2]; r1 += red[g][px][s2 + 1]; }
    float2 o2 = {r0, r1};
    *(float2*)&xp[(((size_t)b * 128 + t) * 128 + hq * 32 + px) * DS + s2] = o2;
}

// ---------------------------------------------------------------------------
// K4: fused gate-compute + tridiagonal scan.
// grid = 768 = bc*2 + parity; 128 thr = 2 waves, wave dl = dir parity+2*dl.
// 2 rows/lane (l, l+64): row exchange intra-wave via DPP (+2 readlane for
// the 63<->64 crossover). ycol double-buffered 8-step batches -> 1 barrier/8.
// NEW: 4-deep register prefetch pipeline (gate sets P0..P3 + 4 X streams),
// each set reloading t+4 right after use; no exp clamps (|act| ~ N(0,1)).
#define ROWDOT(Q0, Q1, Q2, Q3, oGl, oGm, oGr, oL, oU, oD) {                  \
    v2f mx0{Q0.x, Q0.y}, mx1{Q0.z, Q0.w}, mx2{Q1.x, Q1.y}, mx3{Q1.z, Q1.w};  \
    v2f mx4{Q2.x, Q2.y}, mx5{Q2.z, Q2.w}, mx6{Q3.x, Q3.y}, mx7{Q3.z, Q3.w};  \
    v2f aGl = wGl[0] * mx0, aGm = wGm[0] * mx0, aGr = wGr[0] * mx0;          \
    v2f aL = wL[0] * mx0, aU = wU[0] * mx0, aD = wD[0] * mx0;                \
    DACC(1, mx1) DACC(2, mx2) DACC(3, mx3) DACC(4, mx4)                      \
    DACC(5, mx5) DACC(6, mx6) DACC(7, mx7)                                   \
    oGl = aGl.x + aGl.y; oGm = aGm.x + aGm.y; oGr = aGr.x + aGr.y;           \
    oL = aL.x + aL.y; oU = aU.x + aU.y; oD = aD.x + aD.y; }

#define DACC(j, P) { aGl += wGl[j] * P; aGm += wGm[j] * P; aGr += wGr[j] * P; \
    aL += wL[j] * P; aU += wU[j] * P; aD += wD[j] * P; }

// One scan step. GP points at the B-row of this set's NEXT (t+4) column;
// A-row at GP[-1024] (=-4096 B, folds into the signed 13-bit imm). After
// reload, GP advances 4 columns (8192 floats). X streams likewise 4-deep.
#define KSTEP4(kk, A0, A1, A2, A3, B0, B1, B2, B3, GP, XA_, XB_, XQ) {       \
    float sGlA, sGmA, sGrA, sLA, sUA, sDA;                                   \
    float sGlB, sGmB, sGrB, sLB, sUB, sDB;                                   \
    ROWDOT(A0, A1, A2, A3, sGlA, sGmA, sGrA, sLA, sUA, sDA)                  \
    ROWDOT(B0, B1, B2, B3, sGlB, sGmB, sGrB, sLB, sUB, sDB)                  \
    A0 = *(const float4*)&GP[-1024]; A1 = *(const float4*)&GP[-1020];        \
    A2 = *(const float4*)&GP[-1016]; A3 = *(const float4*)&GP[-1012];        \
    B0 = *(const float4*)&GP[0];     B1 = *(const float4*)&GP[4];            \
    B2 = *(const float4*)&GP[8];     B3 = *(const float4*)&GP[12];           \
    GP += 8192;                                                              \
    float elA = __expf(-sGlA);                                               \
    float emA = __expf(-sGmA);                                               \
    float erA = __expf(-sGrA);                                               \
    float elB = __expf(-sGlB);                                               \
    float emB = __expf(-sGmB);                                               \
    float erB = __expf(-sGrB);                                               \
    float tlA = 1.f + elA, tmA = 1.f + emA, trA = 1.f + erA;                 \
    float tlB = 1.f + elB, tmB = 1.f + emB, trB = 1.f + erB;                 \
    float nlA = (l == 0) ? 0.f : tmA * trA;                                  \
    float nmA = tlA * trA;                                                   \
    float nrA = tlA * tmA;                                                   \
    float invA = frcp(nlA + nmA + nrA);                                      \
    float nlB = tmB * trB;                                                   \
    float nmB = tlB * trB;                                                   \
    float nrB = (l == 63) ? 0.f : tlB * tmB;                                 \
    float invB = frcp(nlB + nmB + nrB);                                      \
    float a63 = rdlane(hA, 63);                                              \
    float b0v = rdlane(hB, 0);                                               \
    float upA = dpp_from_lower(hA);                                          \
    float dnA = dpp_from_upper(hA);                                          \
    if (l == 63) dnA = b0v;                                                  \
    float upB = dpp_from_lower(hB);                                          \
    if (l == 0) upB = a63;                                                   \
    float dnB = dpp_from_upper(hB);                                          \
    hA = fmaf(sLA, XA_, (nlA * upA + nmA * hA + nrA * dnA) * invA);          \
    hB = fmaf(sLB, XB_, (nlB * upB + nmB * hB + nrB * dnB) * invB);          \
    ycol[buf][kk][dl][l]      = fmaf(hA, sUA, XA_ * sDA);                    \
    ycol[buf][kk][dl][l + 64] = fmaf(hB, sUB, XB_ * sDB);                    \
    XA_ = XQ[xstep4]; XB_ = XQ[xstep4 + 64]; XQ += xstep4; }

__global__ __launch_bounds__(128) void k4_scan(
        const float* __restrict__ x1, const float* __restrict__ x1T,
        const float* __restrict__ xp,
        const float* __restrict__ w_wup, const float* __restrict__ w_lup,
        const float* __restrict__ w_uup, const float* __restrict__ w_ddown,
        const float* __restrict__ w_m,
        float* __restrict__ ypA, float* __restrict__ ypB) {
    __shared__ float ycol[2][8][2][128];    // 16 KB, double-buffered batches
    int blk = blockIdx.x;
    int parity = blk & 1;
    int bc = blk >> 1;
    int c = bc % CI;
    int b = bc / CI;
    int tid = threadIdx.x;
    int dl = tid >> 6;                      // wave = one direction
    int l = tid & 63;
    int dir = __builtin_amdgcn_readfirstlane(parity + 2 * dl);
    const float* xsrc = (parity ? x1 : x1T) + (size_t)bc * NPIX;
    float* yp = (parity ? ypB : ypA) + (size_t)bc * NPIX;

    int q = dir * CI + c;
    float wm = w_m[dir];
    v2f wGl[8], wGm[8], wGr[8], wL[8], wU[8], wD[8];
#pragma unroll
    for (int j = 0; j < 8; j++) {
        float2 a;
        a = *(const float2*)&w_wup[(size_t)q * DS + 2 * j];            wGl[j] = v2f{a.x, a.y};
        a = *(const float2*)&w_wup[(size_t)(DC + q) * DS + 2 * j];     wGm[j] = v2f{a.x, a.y};
        a = *(const float2*)&w_wup[(size_t)(2 * DC + q) * DS + 2 * j]; wGr[j] = v2f{a.x, a.y};
        a = *(const float2*)&w_lup[(size_t)q * DS + 2 * j];            wL[j]  = v2f{a.x, a.y};
        a = *(const float2*)&w_uup[(size_t)q * DS + 2 * j];            wU[j]  = v2f{a.x * wm, a.y * wm};
        a = *(const float2*)&w_ddown[(size_t)q * DS + 2 * j];          wD[j]  = v2f{a.x * wm, a.y * wm};
    }

    // gate base for row l; B-row (l+64) is +1024 floats
    const float* gb = xp + ((size_t)b * NPIX + l) * DS;
    // per-set reload pointers: B-row of column (s+4)
    const float* g0 = gb + 1024 + 4 * 2048;
    const float* g1 = gb + 1024 + 5 * 2048;
    const float* g2 = gb + 1024 + 6 * 2048;
    const float* g3 = gb + 1024 + 7 * 2048;
    int xstep = dl ? -128 : 128;
    int xstep4 = 4 * xstep;
    const float* xbase = xsrc + (dl ? 127 * 128 : 0) + l;
    const float* xq0 = xbase;
    const float* xq1 = xbase + xstep;
    const float* xq2 = xbase + 2 * xstep;
    const float* xq3 = xbase + 3 * xstep;
    float* ypp = yp + tid;

    // initial gate regs: sets 0..3 = columns t=0..3
    float4 pA0[4], pA1[4], pA2[4], pA3[4], pB0[4], pB1[4], pB2[4], pB3[4];
#define LOADSET(s) { const float4* _p = (const float4*)&gb[(s) * 2048];      \
    pA0[s] = _p[0]; pA1[s] = _p[1]; pA2[s] = _p[2]; pA3[s] = _p[3];          \
    const float4* _q = (const float4*)&gb[(s) * 2048 + 1024];                \
    pB0[s] = _q[0]; pB1[s] = _q[1]; pB2[s] = _q[2]; pB3[s] = _q[3]; }
    LOADSET(0) LOADSET(1) LOADSET(2) LOADSET(3)
#undef LOADSET
    float Xa0 = xq0[0], Xb0 = xq0[64];
    float Xa1 = xq1[0], Xb1 = xq1[64];
    float Xa2 = xq2[0], Xb2 = xq2[64];
    float Xa3 = xq3[0], Xb3 = xq3[64];

    float hA = 0.f, hB = 0.f;

    for (int tb = 0; tb < 16; tb++) {
        int buf = tb & 1;
        KSTEP4(0, pA0[0], pA1[0], pA2[0], pA3[0], pB0[0], pB1[0], pB2[0], pB3[0], g0, Xa0, Xb0, xq0)
        KSTEP4(1, pA0[1], pA1[1], pA2[1], pA3[1], pB0[1], pB1[1], pB2[1], pB3[1], g1, Xa1, Xb1, xq1)
        KSTEP4(2, pA0[2], pA1[2], pA2[2], pA3[2], pB0[2], pB1[2], pB2[2], pB3[2], g2, Xa2, Xb2, xq2)
        KSTEP4(3, pA0[3], pA1[3], pA2[3], pA3[3], pB0[3], pB1[3], pB2[3], pB3[3], g3, Xa3, Xb3, xq3)
        KSTEP4(4, pA0[0], pA1[0], pA2[0], pA3[0], pB0[0], pB1[0], pB2[0], pB3[0], g0, Xa0, Xb0, xq0)
        KSTEP4(5, pA0[1], pA1[1], pA2[1], pA3[1], pB0[1], pB1[1], pB2[1], pB3[1], g1, Xa1, Xb1, xq1)
        KSTEP4(6, pA0[2], pA1[2], pA2[2], pA3[2], pB0[2], pB1[2], pB2[2], pB3[2], g2, Xa2, Xb2, xq2)
        KSTEP4(7, pA0[3], pA1[3], pA2[3], pA3[3], pB0[3], pB1[3], pB2[3], pB3[3], g3, Xa3, Xb3, xq3)
        __syncthreads();
#pragma unroll
        for (int k = 0; k < 8; k++)
            ypp[k * 128] = ycol[buf][k][0][tid] + ycol[buf][k][1][tid];
        ypp += 1024;
    }
}

// ---------------------------------------------------------------------------
// K5a: merge partials (ym = ypA+ypB) + per-pixel LN stats (mu, rstd).
// grid = B*512 px-chunks(32); 256 thr = 32 px x 8 c-groups(24). Deep ILP.
__global__ __launch_bounds__(256) void k5a_stats(const float* __restrict__ ypA,
                                                 const float* __restrict__ ypB,
                                                 float* __restrict__ ym,
                                                 float* __restrict__ mu,
                                                 float* __restrict__ rstd) {
    __shared__ float s_sum[8][32];
    __shared__ float s_ssq[8][32];
    int blk = blockIdx.x;
    int b = blk >> 9;
    int px0 = (blk & 511) * 32;
    int tid = threadIdx.x;
    int pl = tid & 31, cg = tid >> 5;
    int c0 = cg * 24;
    size_t base = ((size_t)b * CI + c0) * NPIX + px0 + pl;
    const float* pa = ypA + base;
    const float* pb = ypB + base;
    float* pm = ym + base;
    float va[24], vb[24];
#pragma unroll
    for (int j = 0; j < 24; j++) va[j] = pa[(size_t)j * NPIX];
#pragma unroll
    for (int j = 0; j < 24; j++) vb[j] = pb[(size_t)j * NPIX];
    float sum = 0.f, ssq = 0.f;
#pragma unroll
    for (int j = 0; j < 24; j++) {
        float v = va[j] + vb[j];
        pm[(size_t)j * NPIX] = v;
        sum += v;
        ssq = fmaf(v, v, ssq);
    }
    s_sum[cg][pl] = sum; s_ssq[cg][pl] = ssq;
    __syncthreads();
    if (tid < 32) {
        float s = 0.f, qq = 0.f;
#pragma unroll
        for (int g = 0; g < 8; g++) { s += s_sum[g][tid]; qq += s_ssq[g][tid]; }
        float m = s * (1.f / 192.f);
        float var = qq * (1.f / 192.f) - m * m;
        mu[(size_t)b * NPIX + px0 + tid] = m;
        rstd[(size_t)b * NPIX + px0 + tid] = rsqrtf(var + 1e-5f);
    }
}

// ---------------------------------------------------------------------------
// K5b: normalize + write yt + per-(b,c) ssq (ONE atomic per block; depth 2).
__global__ __launch_bounds__(256) void k5b_norm(const float* __restrict__ ym,
                                                const float* __restrict__ mu,
                                                const float* __restrict__ rstd,
                                                const float* __restrict__ ln_w,
                                                const float* __restrict__ ln_b,
                                                float* __restrict__ yt,
                                                float* __restrict__ gxs) {
    __shared__ float red[4];
    int blk = blockIdx.x;
    int ph = blk & 1;
    int bc = blk >> 1;
    int c = bc % CI;
    int b = bc / CI;
    const float* ymp = ym + (size_t)bc * NPIX;
    const float* mup = mu + (size_t)b * NPIX;
    const float* rsp = rstd + (size_t)b * NPIX;
    float* ytp = yt + (size_t)bc * NPIX;
    int tid = threadIdx.x;
    float lw = ln_w[c], lb = ln_b[c];
    float acc = 0.f;
#pragma unroll
    for (int it = 0; it < 8; it++) {
        int p = ph * 8192 + it * 1024 + tid * 4;
        float4 v = *(const float4*)&ymp[p];
        float4 m = *(const float4*)&mup[p];
        float4 r = *(const float4*)&rsp[p];
        float4 vn;
        vn.x = (v.x - m.x) * r.x * lw + lb;
        vn.y = (v.y - m.y) * r.y * lw + lb;
        vn.z = (v.z - m.z) * r.z * lw + lb;
        vn.w = (v.w - m.w) * r.w * lw + lb;
        *(float4*)&ytp[p] = vn;
        acc += vn.x * vn.x + vn.y * vn.y + vn.z * vn.z + vn.w * vn.w;
    }
#pragma unroll
    for (int m = 1; m < 64; m <<= 1) acc += __shfl_xor(acc, m);
    if ((tid & 63) == 0) red[tid >> 6] = acc;
    __syncthreads();
    if (tid == 0) {
        atomicAdd(&gxs[bc], red[0] + red[1] + red[2] + red[3]);
    }
}

// ---------------------------------------------------------------------------
// K6: GRN (per-channel affine) + out-proj conv1x1 + transpose store to NCHW.
// yt layout is [c][t][i]; output must be outp[o][i][t] -> transpose on store.
__global__ __launch_bounds__(256) void k6_out(
        const float* __restrict__ yt, const float* __restrict__ gxs,
        const float* __restrict__ grn_gamma, const float* __restrict__ grn_beta,
        const float* __restrict__ w_out, float* __restrict__ outp) {
    __shared__ float scale_s[CI];
    __shared__ float beta_s[CI];
    __shared__ float redv[1];
    __shared__ float stage[96 * 16 * 8];
    int blk = blockIdx.x;
    int b = blk >> 7;
    int rest = blk & 127;
    int i0 = (rest >> 4) * 16;
    int t0 = (rest & 15) * 8;
    int tid = threadIdx.x;
    if (tid < CI) scale_s[tid] = sqrtf(gxs[b * CI + tid]);
    __syncthreads();
    if (tid < 64) {
        float p = scale_s[tid] + scale_s[tid + 64] + scale_s[tid + 128];
#pragma unroll
        for (int m = 1; m < 64; m <<= 1) p += __shfl_xor(p, m);
        if (tid == 0) redv[0] = p * (1.f / 192.f);
    }
    __syncthreads();
    float mean = redv[0];
    if (tid < CI) {
        float nx = scale_s[tid] / (mean + 1e-6f);
        scale_s[tid] = 1.f + grn_gamma[tid] * nx;
        beta_s[tid] = grn_beta[tid];
    }
    __syncthreads();

    int og = tid >> 6;          // wave-uniform
    int o0 = og * 24;
    int pg = tid & 63;
    int tt = pg >> 3;           // 8 t-cols
    int ii0 = (pg & 7) * 2;     // 16 i-rows, 2 per lane
    float acc[24][2];
#pragma unroll
    for (int j = 0; j < 24; j++) { acc[j][0] = 0.f; acc[j][1] = 0.f; }
    const float* ybase = yt + ((size_t)b * CI) * NPIX + (t0 + tt) * 128 + (i0 + ii0);
#pragma unroll 2
    for (int cc = 0; cc < CI; cc++) {
        float2 yv = *(const float2*)&ybase[(size_t)cc * NPIX];
        float sc = scale_s[cc], be = beta_s[cc];
        float y0 = yv.x * sc + be, y1 = yv.y * sc + be;
#pragma unroll
        for (int j = 0; j < 24; j++) {
            float wv = w_out[(size_t)(o0 + j) * CI + cc];
            acc[j][0] += wv * y0; acc[j][1] += wv * y1;
        }
    }
#pragma unroll
    for (int j = 0; j < 24; j++) {
        stage[((o0 + j) * 16 + ii0 + 0) * 8 + tt] = acc[j][0];
        stage[((o0 + j) * 16 + ii0 + 1) * 8 + tt] = acc[j][1];
    }
    __syncthreads();
    for (int k = 0; k < 48; k++) {
        int L = k * 256 + tid;
        int o = L >> 7;
        int r = L & 127;
        int ii = r >> 3, t2 = r & 7;
        outp[((size_t)(b * CM + o)) * NPIX + (i0 + ii) * 128 + (t0 + t2)] = stage[L];
    }
}

// ---------------------------------------------------------------------------
extern "C" void kernel_launch(void* const* d_in, const int* in_sizes, int n_in,
                              void* d_out, int out_size, void* d_ws, size_t ws_size,
                              hipStream_t stream) {
    const float* x        = (const float*)d_in[0];
    const float* w_in     = (const float*)d_in[1];
    const float* w_dw     = (const float*)d_in[2];
    const float* b_dw     = (const float*)d_in[3];
    const float* w_xdown  = (const float*)d_in[4];
    const float* w_wup    = (const float*)d_in[5];
    const float* w_lup    = (const float*)d_in[6];
    const float* w_uup    = (const float*)d_in[7];
    const float* w_ddown  = (const float*)d_in[8];
    const float* w_m      = (const float*)d_in[9];
    const float* grn_gamma= (const float*)d_in[10];
    const float* grn_beta = (const float*)d_in[11];
    const float* ln_w     = (const float*)d_in[12];
    const float* ln_b     = (const float*)d_in[13];
    const float* w_out    = (const float*)d_in[14];
    float* ws    = (float*)d_ws;
    float* x1pre = ws + OFF_X1PRE;
    float* x1    = ws + OFF_X1;
    float* x1T   = ws + OFF_X1T;
    float* xp    = ws + OFF_XP;
    float* ypA   = ws + OFF_YPA;
    float* ypB   = ws + OFF_YPB;
    float* ym    = ws + OFF_YM;
    float* mu    = ws + OFF_MU;
    float* rstd  = ws + OFF_RSTD;
    float* yt    = ws + OFF_YT;
    float* gxs   = ws + OFF_GXS;
    float* outp  = (float*)d_out;

    hipMemsetAsync(gxs, 0, BB * CI * sizeof(float), stream);
    dim3 g1(256, 6);
    k1_conv_in<<<g1, 256, 0, stream>>>(x, w_in, x1pre);
    k2_dwconv<<<BB * CI * 4, 256, 0, stream>>>(x1pre, w_dw, b_dw, x1, x1T);
    k3_xp<<<BB * 128 * 4, 256, 0, stream>>>(x1T, w_xdown, xp);
    k4_scan<<<BB * CI * 2, 128, 0, stream>>>(x1, x1T, xp, w_wup, w_lup, w_uup,
                                             w_ddown, w_m, ypA, ypB);
    k5a_stats<<<BB * 512, 256, 0, stream>>>(ypA, ypB, ym, mu, rstd);
    k5b_norm<<<BB * CI * 2, 256, 0, stream>>>(ym, mu, rstd, ln_w, ln_b, yt, gxs);
    k6_out<<<256, 256, 0, stream>>>(yt, gxs, grn_gamma, grn_beta, w_out, outp);
}

// Round 11
// 263.649 us; speedup vs baseline: 1.2945x; 1.2945x over previous
//
#include <hip/hip_runtime.h>

typedef float v2f __attribute__((ext_vector_type(2)));

// Problem constants
constexpr int BB = 2;        // batch
constexpr int CM = 96;       // d_model
constexpr int CI = 192;      // d_inner
constexpr int NPIX = 128 * 128;   // 16384
constexpr int DS = 16;            // d_state
constexpr int DC = 4 * CI;        // 768

// workspace layout (floats). Overlays:
//   ypB <- x1pre (dead after K2);  ym <- x1T (dead after K4);
//   mu/rstd <- xp (dead after K4).
constexpr size_t OFF_X1PRE = 0;
constexpr size_t OFF_X1    = 6291456;
constexpr size_t OFF_X1T   = 12582912;
constexpr size_t OFF_XP    = 18874368;
constexpr size_t OFF_YPA   = 19398656;
constexpr size_t OFF_YPB   = 0;          // alias x1pre
constexpr size_t OFF_YM    = 12582912;   // alias x1T
constexpr size_t OFF_MU    = 18874368;   // alias xp (first 32768)
constexpr size_t OFF_RSTD  = 18874368 + 32768;
constexpr size_t OFF_GXS   = 25690112;

__device__ __forceinline__ float frcp(float x) { return __builtin_amdgcn_rcpf(x); }

// ---------------------------------------------------------------------------
// K1: x1_pre = conv1x1(x, w_in)   (B,96,H,W) -> (B,192,H,W)
// grid (256, 3): 64-channel tiles -> x re-read 3x (was 6x); 8x4 reg tile.
__global__ __launch_bounds__(256) void k1_conv_in(const float* __restrict__ x,
                                                  const float* __restrict__ w_in,
                                                  float* __restrict__ x1pre) {
    __shared__ float xs[16][128];
    __shared__ float wsh[16][64];
    int pt = blockIdx.x;
    int b = pt >> 7;
    int pxb = (pt & 127) * 128;
    int cb = blockIdx.y * 64;
    int tid = threadIdx.x;
    int cl0 = (tid >> 5) * 8;
    int px0 = (tid & 31) * 4;
    float acc[8][4];
#pragma unroll
    for (int i = 0; i < 8; i++)
#pragma unroll
        for (int j = 0; j < 4; j++) acc[i][j] = 0.f;

    for (int m0 = 0; m0 < 96; m0 += 16) {
        {
            int e = tid * 8;
            int ml = e >> 7, pp = e & 127;
            const float* src = &x[((size_t)(b * CM + m0 + ml)) * NPIX + pxb + pp];
            *(float4*)&xs[ml][pp] = *(const float4*)(src);
            *(float4*)&xs[ml][pp + 4] = *(const float4*)(src + 4);
        }
        {
            int cl = tid >> 2, mq = (tid & 3) * 4;
            float4 v = *(const float4*)&w_in[(size_t)(cb + cl) * CM + m0 + mq];
            wsh[mq + 0][cl] = v.x; wsh[mq + 1][cl] = v.y;
            wsh[mq + 2][cl] = v.z; wsh[mq + 3][cl] = v.w;
        }
        __syncthreads();
#pragma unroll
        for (int m = 0; m < 16; m++) {
            float4 wv0 = *(const float4*)&wsh[m][cl0];
            float4 wv1 = *(const float4*)&wsh[m][cl0 + 4];
            float4 xv = *(const float4*)&xs[m][px0];
            float wr[8] = {wv0.x, wv0.y, wv0.z, wv0.w, wv1.x, wv1.y, wv1.z, wv1.w};
            float xr[4] = {xv.x, xv.y, xv.z, xv.w};
#pragma unroll
            for (int i = 0; i < 8; i++)
#pragma unroll
                for (int j = 0; j < 4; j++) acc[i][j] = fmaf(wr[i], xr[j], acc[i][j]);
        }
        __syncthreads();
    }
#pragma unroll
    for (int i = 0; i < 8; i++) {
        float4 v = {acc[i][0], acc[i][1], acc[i][2], acc[i][3]};
        *(float4*)&x1pre[((size_t)(b * CI + cb + cl0 + i)) * NPIX + pxb + px0] = v;
    }
}

// ---------------------------------------------------------------------------
// K2: x1 = dwconv3x3(x1_pre)+b, writes BOTH x1 [h][w] and x1T [w][h].
__global__ __launch_bounds__(256) void k2_dwconv(const float* __restrict__ x1pre,
                                                 const float* __restrict__ w_dw,
                                                 const float* __restrict__ b_dw,
                                                 float* __restrict__ x1,
                                                 float* __restrict__ x1T) {
    __shared__ float inT[66][67];
    __shared__ float outT[64][65];
    int blk = blockIdx.x;
    int bc = blk >> 2;
    int tile = blk & 3;
    int h0 = (tile >> 1) * 64, w0 = (tile & 1) * 64;
    int c = bc % CI;
    const float* src = x1pre + (size_t)bc * NPIX;
    int tid = threadIdx.x;
    for (int idx = tid; idx < 66 * 66; idx += 256) {
        int r = idx / 66, cl = idx - r * 66;
        int hh = h0 - 1 + r, ww = w0 - 1 + cl;
        float v = 0.f;
        if ((unsigned)hh < 128u && (unsigned)ww < 128u) v = src[hh * 128 + ww];
        inT[r][cl] = v;
    }
    float w00 = w_dw[c * 9 + 0], w01 = w_dw[c * 9 + 1], w02 = w_dw[c * 9 + 2];
    float w10 = w_dw[c * 9 + 3], w11 = w_dw[c * 9 + 4], w12 = w_dw[c * 9 + 5];
    float w20 = w_dw[c * 9 + 6], w21 = w_dw[c * 9 + 7], w22 = w_dw[c * 9 + 8];
    float bias = b_dw[c];
    __syncthreads();
    int cl = tid & 63, r0 = tid >> 6;
#pragma unroll 4
    for (int k = 0; k < 16; k++) {
        int r = k * 4 + r0;
        float s = w00 * inT[r][cl]     + w01 * inT[r][cl + 1]     + w02 * inT[r][cl + 2]
                + w10 * inT[r + 1][cl] + w11 * inT[r + 1][cl + 1] + w12 * inT[r + 1][cl + 2]
                + w20 * inT[r + 2][cl] + w21 * inT[r + 2][cl + 1] + w22 * inT[r + 2][cl + 2]
                + bias;
        x1[(size_t)bc * NPIX + (h0 + r) * 128 + w0 + cl] = s;
        outT[r][cl] = s;
    }
    __syncthreads();
#pragma unroll 4
    for (int k = 0; k < 16; k++) {
        int r = k * 4 + r0;
        x1T[(size_t)bc * NPIX + (w0 + r) * 128 + h0 + cl] = outT[cl][r];
    }
}

// ---------------------------------------------------------------------------
// K3: xp = conv1x1(x1, w_xdown) via x1T, stored (b, w, h, 16).
__global__ __launch_bounds__(256) void k3_xp(const float* __restrict__ x1T,
                                             const float* __restrict__ w_xdown,
                                             float* __restrict__ xp) {
    __shared__ float wsh_t[CI * DS];        // [c][s] transposed, 12 KB
    __shared__ float red[8][32][20];        // padded, 20.5 KB
    int blk = blockIdx.x;
    int b = blk >> 9;
    int rest = blk & 511;
    int t = rest >> 2;                      // w index
    int hq = rest & 3;
    int tid = threadIdx.x;
#pragma unroll
    for (int rep = 0; rep < 12; rep++) {
        int e = rep * 256 + tid;            // e = s*CI + c
        int s = e / CI;
        int cc = e - s * CI;
        wsh_t[cc * DS + s] = w_xdown[e];
    }
    int pl = tid & 31;                      // px within quarter
    int cg = tid >> 5;                      // 8 groups
    int c0 = cg * 24;
    int hpix = hq * 32 + pl;
    __syncthreads();
    float acc[DS];
#pragma unroll
    for (int s = 0; s < DS; s++) acc[s] = 0.f;
    const float* xb = x1T + ((size_t)b * CI + c0) * NPIX + t * 128 + hpix;
#pragma unroll 4
    for (int cc = 0; cc < 24; cc++) {
        float v = xb[(size_t)cc * NPIX];
        const float4* wr4 = (const float4*)&wsh_t[(c0 + cc) * DS];
        float4 w0 = wr4[0], w1 = wr4[1], w2 = wr4[2], w3 = wr4[3];
        acc[0] = fmaf(w0.x, v, acc[0]);  acc[1] = fmaf(w0.y, v, acc[1]);
        acc[2] = fmaf(w0.z, v, acc[2]);  acc[3] = fmaf(w0.w, v, acc[3]);
        acc[4] = fmaf(w1.x, v, acc[4]);  acc[5] = fmaf(w1.y, v, acc[5]);
        acc[6] = fmaf(w1.z, v, acc[6]);  acc[7] = fmaf(w1.w, v, acc[7]);
        acc[8] = fmaf(w2.x, v, acc[8]);  acc[9] = fmaf(w2.y, v, acc[9]);
        acc[10] = fmaf(w2.z, v, acc[10]); acc[11] = fmaf(w2.w, v, acc[11]);
        acc[12] = fmaf(w3.x, v, acc[12]); acc[13] = fmaf(w3.y, v, acc[13]);
        acc[14] = fmaf(w3.z, v, acc[14]); acc[15] = fmaf(w3.w, v, acc[15]);
    }
#pragma unroll
    for (int q = 0; q < 4; q++)
        *(float4*)&red[cg][pl][q * 4] = *(float4*)&acc[q * 4];
    __syncthreads();
    int px = tid >> 3;
    int s2 = (tid & 7) * 2;
    float r0 = 0.f, r1 = 0.f;
#pragma unroll
    for (int g = 0; g < 8; g++) { r0 += red[g][px][s2]; r1 += red[g][px][s2 + 1]; }
    float2 o2 = {r0, r1};
    *(float2*)&xp[(((size_t)b * 128 + t) * 128 + hq * 32 + px) * DS + s2] = o2;
}

// ---------------------------------------------------------------------------
// K4: fused gate-compute + tridiagonal scan, dir-PAIR per block (round-8
// proven version: 256 thr, 2x unroll, reload-in-place, numerator-norm).
#define GLOAD(P, ptr) { const v2f* _gp = (const v2f*)(ptr);                  \
    P##0 = _gp[0]; P##1 = _gp[1]; P##2 = _gp[2]; P##3 = _gp[3];              \
    P##4 = _gp[4]; P##5 = _gp[5]; P##6 = _gp[6]; P##7 = _gp[7]; }

#define DACC(j, P) { aGl += wGl[j] * P; aGm += wGm[j] * P; aGr += wGr[j] * P; \
    aL += wL[j] * P; aU += wU[j] * P; aD += wD[j] * P; }

__global__ __launch_bounds__(256, 3) void k4_scan(
        const float* __restrict__ x1, const float* __restrict__ x1T,
        const float* __restrict__ xp,
        const float* __restrict__ w_wup, const float* __restrict__ w_lup,
        const float* __restrict__ w_uup, const float* __restrict__ w_ddown,
        const float* __restrict__ w_m,
        float* __restrict__ ypA, float* __restrict__ ypB) {
    __shared__ float ycol[2][2][128];
    __shared__ float seam[2][2][2];
    int blk = blockIdx.x;
    int parity = blk & 1;
    int bc = blk >> 1;
    int c = bc % CI;
    int b = bc / CI;
    int tid = threadIdx.x;
    int dl = tid >> 7;
    int half = (tid >> 6) & 1;
    int l = tid & 63;
    int i = half * 64 + l;
    int dir = __builtin_amdgcn_readfirstlane(parity + 2 * dl);
    const float* xsrc = (parity ? x1 : x1T) + (size_t)bc * NPIX;
    float* yp = (parity ? ypB : ypA) + (size_t)bc * NPIX;

    int q = dir * CI + c;
    float wm = w_m[dir];
    v2f wGl[8], wGm[8], wGr[8], wL[8], wU[8], wD[8];
#pragma unroll
    for (int j = 0; j < 8; j++) {
        float2 a;
        a = *(const float2*)&w_wup[(size_t)q * DS + 2 * j];            wGl[j] = v2f{a.x, a.y};
        a = *(const float2*)&w_wup[(size_t)(DC + q) * DS + 2 * j];     wGm[j] = v2f{a.x, a.y};
        a = *(const float2*)&w_wup[(size_t)(2 * DC + q) * DS + 2 * j]; wGr[j] = v2f{a.x, a.y};
        a = *(const float2*)&w_lup[(size_t)q * DS + 2 * j];            wL[j]  = v2f{a.x, a.y};
        a = *(const float2*)&w_uup[(size_t)q * DS + 2 * j];            wU[j]  = v2f{a.x * wm, a.y * wm};
        a = *(const float2*)&w_ddown[(size_t)q * DS + 2 * j];          wD[j]  = v2f{a.x * wm, a.y * wm};
    }
    if (tid < 8) ((float*)seam)[tid] = 0.f;
    __syncthreads();

    bool at_top = (i == 0), at_bot = (i == 127);
    bool seam_lo = (half == 0 && l == 63);
    bool seam_hi = (half == 1 && l == 0);

    const float* gbase = xp + ((size_t)b * NPIX + i) * DS;
    const float* gptr = gbase + 4096;                  // points at t+2 rows
    int xstep = dl ? -128 : 128;
    int xstep2 = 2 * xstep;
    const float* xpe = xsrc + (dl ? 127 * 128 : 0) + i;   // even-step X
    const float* xpo = xpe + xstep;                       // odd-step X
    float* ypp = yp + (tid & 127);

    v2f e0, e1, e2, e3, e4, e5, e6, e7;
    v2f o0, o1, o2, o3, o4, o5, o6, o7;
    GLOAD(e, gbase);
    GLOAD(o, gbase + 2048);
    float Xe = xpe[0];
    float Xo = xpo[0];

    float h = 0.f;
    for (int t = 0; t < 128; t += 2) {
        // ---- even step: buf 0, prev seam = seam[1] ----
        {
            v2f aGl = wGl[0] * e0, aGm = wGm[0] * e0, aGr = wGr[0] * e0;
            v2f aL = wL[0] * e0, aU = wU[0] * e0, aD = wD[0] * e0;
            DACC(1, e1) DACC(2, e2) DACC(3, e3) DACC(4, e4)
            DACC(5, e5) DACC(6, e6) DACC(7, e7)
            GLOAD(e, gptr);                       // prefetch t+2 (past-end safe)
            float sGl = aGl.x + aGl.y, sGm = aGm.x + aGm.y, sGr = aGr.x + aGr.y;
            float sL = aL.x + aL.y, sU = aU.x + aU.y, sD = aD.x + aD.y;
            float el = __expf(fminf(-sGl, 40.f));
            float em = __expf(fminf(-sGm, 40.f));
            float er = __expf(fminf(-sGr, 40.f));
            float tl = 1.f + el, tm = 1.f + em, tr = 1.f + er;
            float nl = at_top ? 0.f : tm * tr;
            float nm = tl * tr;
            float nr = at_bot ? 0.f : tl * tm;
            float inv = frcp(nl + nm + nr);
            float up = __shfl_up(h, 1);
            if (l == 0) up = half ? seam[1][dl][0] : 0.f;
            float dn = __shfl_down(h, 1);
            if (l == 63) dn = half ? 0.f : seam[1][dl][1];
            float X = Xe;
            h = fmaf(sL, X, (nl * up + nm * h + nr * dn) * inv);
            Xe = xpe[xstep2];                     // prefetch t+2 X (past-end safe)
            ycol[0][dl][i] = fmaf(h, sU, X * sD);
            if (seam_lo) seam[0][dl][0] = h;
            if (seam_hi) seam[0][dl][1] = h;
        }
        __syncthreads();
        if (tid < 128) ypp[0] = ycol[0][0][tid] + ycol[0][1][tid];
        // ---- odd step: buf 1, prev seam = seam[0] ----
        {
            v2f aGl = wGl[0] * o0, aGm = wGm[0] * o0, aGr = wGr[0] * o0;
            v2f aL = wL[0] * o0, aU = wU[0] * o0, aD = wD[0] * o0;
            DACC(1, o1) DACC(2, o2) DACC(3, o3) DACC(4, o4)
            DACC(5, o5) DACC(6, o6) DACC(7, o7)
            GLOAD(o, gptr + 2048);                // prefetch t+3
            float sGl = aGl.x + aGl.y, sGm = aGm.x + aGm.y, sGr = aGr.x + aGr.y;
            float sL = aL.x + aL.y, sU = aU.x + aU.y, sD = aD.x + aD.y;
            float el = __expf(fminf(-sGl, 40.f));
            float em = __expf(fminf(-sGm, 40.f));
            float er = __expf(fminf(-sGr, 40.f));
            float tl = 1.f + el, tm = 1.f + em, tr = 1.f + er;
            float nl = at_top ? 0.f : tm * tr;
            float nm = tl * tr;
            float nr = at_bot ? 0.f : tl * tm;
            float inv = frcp(nl + nm + nr);
            float up = __shfl_up(h, 1);
            if (l == 0) up = half ? seam[0][dl][0] : 0.f;
            float dn = __shfl_down(h, 1);
            if (l == 63) dn = half ? 0.f : seam[0][dl][1];
            float X = Xo;
            h = fmaf(sL, X, (nl * up + nm * h + nr * dn) * inv);
            Xo = xpo[xstep2];                     // prefetch t+3 X
            ycol[1][dl][i] = fmaf(h, sU, X * sD);
            if (seam_lo) seam[1][dl][0] = h;
            if (seam_hi) seam[1][dl][1] = h;
        }
        gptr += 4096;
        xpe += xstep2;
        xpo += xstep2;
        __syncthreads();
        if (tid < 128) ypp[128] = ycol[1][0][tid] + ycol[1][1][tid];
        ypp += 256;
    }
}

// ---------------------------------------------------------------------------
// K5a: merge partials (ym = ypA+ypB) + per-pixel LN stats (mu, rstd).
__global__ __launch_bounds__(256) void k5a_stats(const float* __restrict__ ypA,
                                                 const float* __restrict__ ypB,
                                                 float* __restrict__ ym,
                                                 float* __restrict__ mu,
                                                 float* __restrict__ rstd) {
    __shared__ float s_sum[8][32];
    __shared__ float s_ssq[8][32];
    int blk = blockIdx.x;
    int b = blk >> 9;
    int px0 = (blk & 511) * 32;
    int tid = threadIdx.x;
    int pl = tid & 31, cg = tid >> 5;
    int c0 = cg * 24;
    size_t base = ((size_t)b * CI + c0) * NPIX + px0 + pl;
    const float* pa = ypA + base;
    const float* pb = ypB + base;
    float* pm = ym + base;
    float va[24], vb[24];
#pragma unroll
    for (int j = 0; j < 24; j++) va[j] = pa[(size_t)j * NPIX];
#pragma unroll
    for (int j = 0; j < 24; j++) vb[j] = pb[(size_t)j * NPIX];
    float sum = 0.f, ssq = 0.f;
#pragma unroll
    for (int j = 0; j < 24; j++) {
        float v = va[j] + vb[j];
        pm[(size_t)j * NPIX] = v;
        sum += v;
        ssq = fmaf(v, v, ssq);
    }
    s_sum[cg][pl] = sum; s_ssq[cg][pl] = ssq;
    __syncthreads();
    if (tid < 32) {
        float s = 0.f, qq = 0.f;
#pragma unroll
        for (int g = 0; g < 8; g++) { s += s_sum[g][tid]; qq += s_ssq[g][tid]; }
        float m = s * (1.f / 192.f);
        float var = qq * (1.f / 192.f) - m * m;
        mu[(size_t)b * NPIX + px0 + tid] = m;
        rstd[(size_t)b * NPIX + px0 + tid] = rsqrtf(var + 1e-5f);
    }
}

// ---------------------------------------------------------------------------
// K5b: per-(b,c) ssq of NORMALIZED values (no yt write — k6 re-derives).
// One atomic per block; depth 2 per gxs address.
__global__ __launch_bounds__(256) void k5b_norm(const float* __restrict__ ym,
                                                const float* __restrict__ mu,
                                                const float* __restrict__ rstd,
                                                const float* __restrict__ ln_w,
                                                const float* __restrict__ ln_b,
                                                float* __restrict__ gxs) {
    __shared__ float red[4];
    int blk = blockIdx.x;
    int ph = blk & 1;
    int bc = blk >> 1;
    int c = bc % CI;
    int b = bc / CI;
    const float* ymp = ym + (size_t)bc * NPIX;
    const float* mup = mu + (size_t)b * NPIX;
    const float* rsp = rstd + (size_t)b * NPIX;
    int tid = threadIdx.x;
    float lw = ln_w[c], lb = ln_b[c];
    float acc = 0.f;
#pragma unroll
    for (int it = 0; it < 8; it++) {
        int p = ph * 8192 + it * 1024 + tid * 4;
        float4 v = *(const float4*)&ymp[p];
        float4 m = *(const float4*)&mup[p];
        float4 r = *(const float4*)&rsp[p];
        float vn0 = (v.x - m.x) * r.x * lw + lb;
        float vn1 = (v.y - m.y) * r.y * lw + lb;
        float vn2 = (v.z - m.z) * r.z * lw + lb;
        float vn3 = (v.w - m.w) * r.w * lw + lb;
        acc += vn0 * vn0 + vn1 * vn1 + vn2 * vn2 + vn3 * vn3;
    }
#pragma unroll
    for (int m = 1; m < 64; m <<= 1) acc += __shfl_xor(acc, m);
    if ((tid & 63) == 0) red[tid >> 6] = acc;
    __syncthreads();
    if (tid == 0) {
        atomicAdd(&gxs[bc], red[0] + red[1] + red[2] + red[3]);
    }
}

// ---------------------------------------------------------------------------
// K6: LN+GRN folded to per-channel affine on (ym,mu,rstd) + out-proj conv1x1
// + transpose store to NCHW. out = (v - mu)*rstd*A_c + B_c, A = lw*sc,
// B = lb*sc + beta; then conv with w_out.
__global__ __launch_bounds__(256) void k6_out(
        const float* __restrict__ ym, const float* __restrict__ mu,
        const float* __restrict__ rstd, const float* __restrict__ gxs,
        const float* __restrict__ grn_gamma, const float* __restrict__ grn_beta,
        const float* __restrict__ ln_w, const float* __restrict__ ln_b,
        const float* __restrict__ w_out, float* __restrict__ outp) {
    __shared__ float scale_s[CI];   // A_c
    __shared__ float beta_s[CI];    // B_c
    __shared__ float redv[1];
    __shared__ float stage[96 * 16 * 8];
    int blk = blockIdx.x;
    int b = blk >> 7;
    int rest = blk & 127;
    int i0 = (rest >> 4) * 16;
    int t0 = (rest & 15) * 8;
    int tid = threadIdx.x;
    if (tid < CI) scale_s[tid] = sqrtf(gxs[b * CI + tid]);
    __syncthreads();
    if (tid < 64) {
        float p = scale_s[tid] + scale_s[tid + 64] + scale_s[tid + 128];
#pragma unroll
        for (int m = 1; m < 64; m <<= 1) p += __shfl_xor(p, m);
        if (tid == 0) redv[0] = p * (1.f / 192.f);
    }
    __syncthreads();
    float mean = redv[0];
    if (tid < CI) {
        float nx = scale_s[tid] / (mean + 1e-6f);
        float sc = 1.f + grn_gamma[tid] * nx;
        scale_s[tid] = ln_w[tid] * sc;
        beta_s[tid] = ln_b[tid] * sc + grn_beta[tid];
    }
    __syncthreads();

    int og = tid >> 6;          // wave-uniform
    int o0 = og * 24;
    int pg = tid & 63;
    int tt = pg >> 3;           // 8 t-cols
    int ii0 = (pg & 7) * 2;     // 16 i-rows, 2 per lane
    float acc[24][2];
#pragma unroll
    for (int j = 0; j < 24; j++) { acc[j][0] = 0.f; acc[j][1] = 0.f; }
    int pbase = (t0 + tt) * 128 + (i0 + ii0);
    const float* ybase = ym + ((size_t)b * CI) * NPIX + pbase;
    float2 mm = *(const float2*)&mu[(size_t)b * NPIX + pbase];
    float2 rr = *(const float2*)&rstd[(size_t)b * NPIX + pbase];
#pragma unroll 2
    for (int cc = 0; cc < CI; cc++) {
        float2 yv = *(const float2*)&ybase[(size_t)cc * NPIX];
        float A = scale_s[cc], Bc = beta_s[cc];
        float y0 = fmaf((yv.x - mm.x) * rr.x, A, Bc);
        float y1 = fmaf((yv.y - mm.y) * rr.y, A, Bc);
#pragma unroll
        for (int j = 0; j < 24; j++) {
            float wv = w_out[(size_t)(o0 + j) * CI + cc];
            acc[j][0] += wv * y0; acc[j][1] += wv * y1;
        }
    }
#pragma unroll
    for (int j = 0; j < 24; j++) {
        stage[((o0 + j) * 16 + ii0 + 0) * 8 + tt] = acc[j][0];
        stage[((o0 + j) * 16 + ii0 + 1) * 8 + tt] = acc[j][1];
    }
    __syncthreads();
    for (int k = 0; k < 48; k++) {
        int L = k * 256 + tid;
        int o = L >> 7;
        int r = L & 127;
        int ii = r >> 3, t2 = r & 7;
        outp[((size_t)(b * CM + o)) * NPIX + (i0 + ii) * 128 + (t0 + t2)] = stage[L];
    }
}

// ---------------------------------------------------------------------------
extern "C" void kernel_launch(void* const* d_in, const int* in_sizes, int n_in,
                              void* d_out, int out_size, void* d_ws, size_t ws_size,
                              hipStream_t stream) {
    const float* x        = (const float*)d_in[0];
    const float* w_in     = (const float*)d_in[1];
    const float* w_dw     = (const float*)d_in[2];
    const float* b_dw     = (const float*)d_in[3];
    const float* w_xdown  = (const float*)d_in[4];
    const float* w_wup    = (const float*)d_in[5];
    const float* w_lup    = (const float*)d_in[6];
    const float* w_uup    = (const float*)d_in[7];
    const float* w_ddown  = (const float*)d_in[8];
    const float* w_m      = (const float*)d_in[9];
    const float* grn_gamma= (const float*)d_in[10];
    const float* grn_beta = (const float*)d_in[11];
    const float* ln_w     = (const float*)d_in[12];
    const float* ln_b     = (const float*)d_in[13];
    const float* w_out    = (const float*)d_in[14];
    float* ws    = (float*)d_ws;
    float* x1pre = ws + OFF_X1PRE;
    float* x1    = ws + OFF_X1;
    float* x1T   = ws + OFF_X1T;
    float* xp    = ws + OFF_XP;
    float* ypA   = ws + OFF_YPA;
    float* ypB   = ws + OFF_YPB;
    float* ym    = ws + OFF_YM;
    float* mu    = ws + OFF_MU;
    float* rstd  = ws + OFF_RSTD;
    float* gxs   = ws + OFF_GXS;
    float* outp  = (float*)d_out;

    hipMemsetAsync(gxs, 0, BB * CI * sizeof(float), stream);
    dim3 g1(256, 3);
    k1_conv_in<<<g1, 256, 0, stream>>>(x, w_in, x1pre);
    k2_dwconv<<<BB * CI * 4, 256, 0, stream>>>(x1pre, w_dw, b_dw, x1, x1T);
    k3_xp<<<BB * 128 * 4, 256, 0, stream>>>(x1T, w_xdown, xp);
    k4_scan<<<BB * CI * 2, 256, 0, stream>>>(x1, x1T, xp, w_wup, w_lup, w_uup,
                                             w_ddown, w_m, ypA, ypB);
    k5a_stats<<<BB * 512, 256, 0, stream>>>(ypA, ypB, ym, mu, rstd);
    k5b_norm<<<BB * CI * 2, 256, 0, stream>>>(ym, mu, rstd, ln_w, ln_b, gxs);
    k6_out<<<256, 256, 0, stream>>>(ym, mu, rstd, gxs, grn_gamma, grn_beta,
                                    ln_w, ln_b, w_out, outp);
}

// Round 12
// 262.408 us; speedup vs baseline: 1.3006x; 1.0047x over previous
//
#include <hip/hip_runtime.h>

typedef float v2f __attribute__((ext_vector_type(2)));

// Problem constants
constexpr int BB = 2;        // batch
constexpr int CM = 96;       // d_model
constexpr int CI = 192;      // d_inner
constexpr int NPIX = 128 * 128;   // 16384
constexpr int DS = 16;            // d_state
constexpr int DC = 4 * CI;        // 768

// workspace layout (floats). Overlays:
//   ypB <- x1pre (dead after K2);  ym <- x1T (dead after K4);
//   mu/rstd <- xp (dead after K4).
constexpr size_t OFF_X1PRE = 0;
constexpr size_t OFF_X1    = 6291456;
constexpr size_t OFF_X1T   = 12582912;
constexpr size_t OFF_XP    = 18874368;
constexpr size_t OFF_YPA   = 19398656;
constexpr size_t OFF_YPB   = 0;          // alias x1pre
constexpr size_t OFF_YM    = 12582912;   // alias x1T
constexpr size_t OFF_MU    = 18874368;   // alias xp (first 32768)
constexpr size_t OFF_RSTD  = 18874368 + 32768;
constexpr size_t OFF_GXS   = 25690112;

__device__ __forceinline__ float frcp(float x) { return __builtin_amdgcn_rcpf(x); }
// DPP whole-wave shifts (proven in round-9 kernel): from_lower = lane n reads
// lane n-1 (lane0 -> 0), from_upper = lane n reads lane n+1 (lane63 -> 0).
__device__ __forceinline__ float dpp_from_lower(float x) {
    return __int_as_float(__builtin_amdgcn_update_dpp(
        0, __float_as_int(x), 0x138, 0xf, 0xf, false));   // wave_shr1
}
__device__ __forceinline__ float dpp_from_upper(float x) {
    return __int_as_float(__builtin_amdgcn_update_dpp(
        0, __float_as_int(x), 0x130, 0xf, 0xf, false));   // wave_shl1
}

// ---------------------------------------------------------------------------
// K1: x1_pre = conv1x1(x, w_in)   (B,96,H,W) -> (B,192,H,W)
// grid (256, 3): 64-channel tiles -> x re-read 3x; 8x4 reg tile.
__global__ __launch_bounds__(256) void k1_conv_in(const float* __restrict__ x,
                                                  const float* __restrict__ w_in,
                                                  float* __restrict__ x1pre) {
    __shared__ float xs[16][128];
    __shared__ float wsh[16][64];
    int pt = blockIdx.x;
    int b = pt >> 7;
    int pxb = (pt & 127) * 128;
    int cb = blockIdx.y * 64;
    int tid = threadIdx.x;
    int cl0 = (tid >> 5) * 8;
    int px0 = (tid & 31) * 4;
    float acc[8][4];
#pragma unroll
    for (int i = 0; i < 8; i++)
#pragma unroll
        for (int j = 0; j < 4; j++) acc[i][j] = 0.f;

    for (int m0 = 0; m0 < 96; m0 += 16) {
        {
            int e = tid * 8;
            int ml = e >> 7, pp = e & 127;
            const float* src = &x[((size_t)(b * CM + m0 + ml)) * NPIX + pxb + pp];
            *(float4*)&xs[ml][pp] = *(const float4*)(src);
            *(float4*)&xs[ml][pp + 4] = *(const float4*)(src + 4);
        }
        {
            int cl = tid >> 2, mq = (tid & 3) * 4;
            float4 v = *(const float4*)&w_in[(size_t)(cb + cl) * CM + m0 + mq];
            wsh[mq + 0][cl] = v.x; wsh[mq + 1][cl] = v.y;
            wsh[mq + 2][cl] = v.z; wsh[mq + 3][cl] = v.w;
        }
        __syncthreads();
#pragma unroll
        for (int m = 0; m < 16; m++) {
            float4 wv0 = *(const float4*)&wsh[m][cl0];
            float4 wv1 = *(const float4*)&wsh[m][cl0 + 4];
            float4 xv = *(const float4*)&xs[m][px0];
            float wr[8] = {wv0.x, wv0.y, wv0.z, wv0.w, wv1.x, wv1.y, wv1.z, wv1.w};
            float xr[4] = {xv.x, xv.y, xv.z, xv.w};
#pragma unroll
            for (int i = 0; i < 8; i++)
#pragma unroll
                for (int j = 0; j < 4; j++) acc[i][j] = fmaf(wr[i], xr[j], acc[i][j]);
        }
        __syncthreads();
    }
#pragma unroll
    for (int i = 0; i < 8; i++) {
        float4 v = {acc[i][0], acc[i][1], acc[i][2], acc[i][3]};
        *(float4*)&x1pre[((size_t)(b * CI + cb + cl0 + i)) * NPIX + pxb + px0] = v;
    }
}

// ---------------------------------------------------------------------------
// K2: x1 = dwconv3x3(x1_pre)+b, writes BOTH x1 [h][w] and x1T [w][h].
__global__ __launch_bounds__(256) void k2_dwconv(const float* __restrict__ x1pre,
                                                 const float* __restrict__ w_dw,
                                                 const float* __restrict__ b_dw,
                                                 float* __restrict__ x1,
                                                 float* __restrict__ x1T) {
    __shared__ float inT[66][67];
    __shared__ float outT[64][65];
    int blk = blockIdx.x;
    int bc = blk >> 2;
    int tile = blk & 3;
    int h0 = (tile >> 1) * 64, w0 = (tile & 1) * 64;
    int c = bc % CI;
    const float* src = x1pre + (size_t)bc * NPIX;
    int tid = threadIdx.x;
    for (int idx = tid; idx < 66 * 66; idx += 256) {
        int r = idx / 66, cl = idx - r * 66;
        int hh = h0 - 1 + r, ww = w0 - 1 + cl;
        float v = 0.f;
        if ((unsigned)hh < 128u && (unsigned)ww < 128u) v = src[hh * 128 + ww];
        inT[r][cl] = v;
    }
    float w00 = w_dw[c * 9 + 0], w01 = w_dw[c * 9 + 1], w02 = w_dw[c * 9 + 2];
    float w10 = w_dw[c * 9 + 3], w11 = w_dw[c * 9 + 4], w12 = w_dw[c * 9 + 5];
    float w20 = w_dw[c * 9 + 6], w21 = w_dw[c * 9 + 7], w22 = w_dw[c * 9 + 8];
    float bias = b_dw[c];
    __syncthreads();
    int cl = tid & 63, r0 = tid >> 6;
#pragma unroll 4
    for (int k = 0; k < 16; k++) {
        int r = k * 4 + r0;
        float s = w00 * inT[r][cl]     + w01 * inT[r][cl + 1]     + w02 * inT[r][cl + 2]
                + w10 * inT[r + 1][cl] + w11 * inT[r + 1][cl + 1] + w12 * inT[r + 1][cl + 2]
                + w20 * inT[r + 2][cl] + w21 * inT[r + 2][cl + 1] + w22 * inT[r + 2][cl + 2]
                + bias;
        x1[(size_t)bc * NPIX + (h0 + r) * 128 + w0 + cl] = s;
        outT[r][cl] = s;
    }
    __syncthreads();
#pragma unroll 4
    for (int k = 0; k < 16; k++) {
        int r = k * 4 + r0;
        x1T[(size_t)bc * NPIX + (w0 + r) * 128 + h0 + cl] = outT[cl][r];
    }
}

// ---------------------------------------------------------------------------
// K3: xp = conv1x1(x1, w_xdown) via x1T, stored (b, w, h, 16).
__global__ __launch_bounds__(256) void k3_xp(const float* __restrict__ x1T,
                                             const float* __restrict__ w_xdown,
                                             float* __restrict__ xp) {
    __shared__ float wsh_t[CI * DS];        // [c][s] transposed, 12 KB
    __shared__ float red[8][32][20];        // padded, 20.5 KB
    int blk = blockIdx.x;
    int b = blk >> 9;
    int rest = blk & 511;
    int t = rest >> 2;                      // w index
    int hq = rest & 3;
    int tid = threadIdx.x;
#pragma unroll
    for (int rep = 0; rep < 12; rep++) {
        int e = rep * 256 + tid;            // e = s*CI + c
        int s = e / CI;
        int cc = e - s * CI;
        wsh_t[cc * DS + s] = w_xdown[e];
    }
    int pl = tid & 31;                      // px within quarter
    int cg = tid >> 5;                      // 8 groups
    int c0 = cg * 24;
    int hpix = hq * 32 + pl;
    __syncthreads();
    float acc[DS];
#pragma unroll
    for (int s = 0; s < DS; s++) acc[s] = 0.f;
    const float* xb = x1T + ((size_t)b * CI + c0) * NPIX + t * 128 + hpix;
#pragma unroll 4
    for (int cc = 0; cc < 24; cc++) {
        float v = xb[(size_t)cc * NPIX];
        const float4* wr4 = (const float4*)&wsh_t[(c0 + cc) * DS];
        float4 w0 = wr4[0], w1 = wr4[1], w2 = wr4[2], w3 = wr4[3];
        acc[0] = fmaf(w0.x, v, acc[0]);  acc[1] = fmaf(w0.y, v, acc[1]);
        acc[2] = fmaf(w0.z, v, acc[2]);  acc[3] = fmaf(w0.w, v, acc[3]);
        acc[4] = fmaf(w1.x, v, acc[4]);  acc[5] = fmaf(w1.y, v, acc[5]);
        acc[6] = fmaf(w1.z, v, acc[6]);  acc[7] = fmaf(w1.w, v, acc[7]);
        acc[8] = fmaf(w2.x, v, acc[8]);  acc[9] = fmaf(w2.y, v, acc[9]);
        acc[10] = fmaf(w2.z, v, acc[10]); acc[11] = fmaf(w2.w, v, acc[11]);
        acc[12] = fmaf(w3.x, v, acc[12]); acc[13] = fmaf(w3.y, v, acc[13]);
        acc[14] = fmaf(w3.z, v, acc[14]); acc[15] = fmaf(w3.w, v, acc[15]);
    }
#pragma unroll
    for (int q = 0; q < 4; q++)
        *(float4*)&red[cg][pl][q * 4] = *(float4*)&acc[q * 4];
    __syncthreads();
    int px = tid >> 3;
    int s2 = (tid & 7) * 2;
    float r0 = 0.f, r1 = 0.f;
#pragma unroll
    for (int g = 0; g < 8; g++) { r0 += red[g][px][s2]; r1 += red[g][px][s2 + 1]; }
    float2 o2 = {r0, r1};
    *(float2*)&xp[(((size_t)b * 128 + t) * 128 + hq * 32 + px) * DS + s2] = o2;
}

// ---------------------------------------------------------------------------
// K4: fused gate-compute + tridiagonal scan, dir-PAIR per block (round-8
// structure). CHANGE r12: __shfl_up/down -> DPP wave shifts (no lgkm wait
// on the h-recurrence critical chain); seam selects unchanged.
#define GLOAD(P, ptr) { const v2f* _gp = (const v2f*)(ptr);                  \
    P##0 = _gp[0]; P##1 = _gp[1]; P##2 = _gp[2]; P##3 = _gp[3];              \
    P##4 = _gp[4]; P##5 = _gp[5]; P##6 = _gp[6]; P##7 = _gp[7]; }

#define DACC(j, P) { aGl += wGl[j] * P; aGm += wGm[j] * P; aGr += wGr[j] * P; \
    aL += wL[j] * P; aU += wU[j] * P; aD += wD[j] * P; }

__global__ __launch_bounds__(256, 3) void k4_scan(
        const float* __restrict__ x1, const float* __restrict__ x1T,
        const float* __restrict__ xp,
        const float* __restrict__ w_wup, const float* __restrict__ w_lup,
        const float* __restrict__ w_uup, const float* __restrict__ w_ddown,
        const float* __restrict__ w_m,
        float* __restrict__ ypA, float* __restrict__ ypB) {
    __shared__ float ycol[2][2][128];
    __shared__ float seam[2][2][2];
    int blk = blockIdx.x;
    int parity = blk & 1;
    int bc = blk >> 1;
    int c = bc % CI;
    int b = bc / CI;
    int tid = threadIdx.x;
    int dl = tid >> 7;
    int half = (tid >> 6) & 1;
    int l = tid & 63;
    int i = half * 64 + l;
    int dir = __builtin_amdgcn_readfirstlane(parity + 2 * dl);
    const float* xsrc = (parity ? x1 : x1T) + (size_t)bc * NPIX;
    float* yp = (parity ? ypB : ypA) + (size_t)bc * NPIX;

    int q = dir * CI + c;
    float wm = w_m[dir];
    v2f wGl[8], wGm[8], wGr[8], wL[8], wU[8], wD[8];
#pragma unroll
    for (int j = 0; j < 8; j++) {
        float2 a;
        a = *(const float2*)&w_wup[(size_t)q * DS + 2 * j];            wGl[j] = v2f{a.x, a.y};
        a = *(const float2*)&w_wup[(size_t)(DC + q) * DS + 2 * j];     wGm[j] = v2f{a.x, a.y};
        a = *(const float2*)&w_wup[(size_t)(2 * DC + q) * DS + 2 * j]; wGr[j] = v2f{a.x, a.y};
        a = *(const float2*)&w_lup[(size_t)q * DS + 2 * j];            wL[j]  = v2f{a.x, a.y};
        a = *(const float2*)&w_uup[(size_t)q * DS + 2 * j];            wU[j]  = v2f{a.x * wm, a.y * wm};
        a = *(const float2*)&w_ddown[(size_t)q * DS + 2 * j];          wD[j]  = v2f{a.x * wm, a.y * wm};
    }
    if (tid < 8) ((float*)seam)[tid] = 0.f;
    __syncthreads();

    bool at_top = (i == 0), at_bot = (i == 127);
    bool seam_lo = (half == 0 && l == 63);
    bool seam_hi = (half == 1 && l == 0);

    const float* gbase = xp + ((size_t)b * NPIX + i) * DS;
    const float* gptr = gbase + 4096;                  // points at t+2 rows
    int xstep = dl ? -128 : 128;
    int xstep2 = 2 * xstep;
    const float* xpe = xsrc + (dl ? 127 * 128 : 0) + i;   // even-step X
    const float* xpo = xpe + xstep;                       // odd-step X
    float* ypp = yp + (tid & 127);

    v2f e0, e1, e2, e3, e4, e5, e6, e7;
    v2f o0, o1, o2, o3, o4, o5, o6, o7;
    GLOAD(e, gbase);
    GLOAD(o, gbase + 2048);
    float Xe = xpe[0];
    float Xo = xpo[0];

    float h = 0.f;
    for (int t = 0; t < 128; t += 2) {
        // ---- even step: buf 0, prev seam = seam[1] ----
        {
            v2f aGl = wGl[0] * e0, aGm = wGm[0] * e0, aGr = wGr[0] * e0;
            v2f aL = wL[0] * e0, aU = wU[0] * e0, aD = wD[0] * e0;
            DACC(1, e1) DACC(2, e2) DACC(3, e3) DACC(4, e4)
            DACC(5, e5) DACC(6, e6) DACC(7, e7)
            GLOAD(e, gptr);                       // prefetch t+2 (past-end safe)
            float sGl = aGl.x + aGl.y, sGm = aGm.x + aGm.y, sGr = aGr.x + aGr.y;
            float sL = aL.x + aL.y, sU = aU.x + aU.y, sD = aD.x + aD.y;
            float el = __expf(fminf(-sGl, 40.f));
            float em = __expf(fminf(-sGm, 40.f));
            float er = __expf(fminf(-sGr, 40.f));
            float tl = 1.f + el, tm = 1.f + em, tr = 1.f + er;
            float nl = at_top ? 0.f : tm * tr;
            float nm = tl * tr;
            float nr = at_bot ? 0.f : tl * tm;
            float inv = frcp(nl + nm + nr);
            float up = dpp_from_lower(h);
            if (l == 0) up = half ? seam[1][dl][0] : 0.f;
            float dn = dpp_from_upper(h);
            if (l == 63) dn = half ? 0.f : seam[1][dl][1];
            float X = Xe;
            h = fmaf(sL, X, (nl * up + nm * h + nr * dn) * inv);
            Xe = xpe[xstep2];                     // prefetch t+2 X (past-end safe)
            ycol[0][dl][i] = fmaf(h, sU, X * sD);
            if (seam_lo) seam[0][dl][0] = h;
            if (seam_hi) seam[0][dl][1] = h;
        }
        __syncthreads();
        if (tid < 128) ypp[0] = ycol[0][0][tid] + ycol[0][1][tid];
        // ---- odd step: buf 1, prev seam = seam[0] ----
        {
            v2f aGl = wGl[0] * o0, aGm = wGm[0] * o0, aGr = wGr[0] * o0;
            v2f aL = wL[0] * o0, aU = wU[0] * o0, aD = wD[0] * o0;
            DACC(1, o1) DACC(2, o2) DACC(3, o3) DACC(4, o4)
            DACC(5, o5) DACC(6, o6) DACC(7, o7)
            GLOAD(o, gptr + 2048);                // prefetch t+3
            float sGl = aGl.x + aGl.y, sGm = aGm.x + aGm.y, sGr = aGr.x + aGr.y;
            float sL = aL.x + aL.y, sU = aU.x + aU.y, sD = aD.x + aD.y;
            float el = __expf(fminf(-sGl, 40.f));
            float em = __expf(fminf(-sGm, 40.f));
            float er = __expf(fminf(-sGr, 40.f));
            float tl = 1.f + el, tm = 1.f + em, tr = 1.f + er;
            float nl = at_top ? 0.f : tm * tr;
            float nm = tl * tr;
            float nr = at_bot ? 0.f : tl * tm;
            float inv = frcp(nl + nm + nr);
            float up = dpp_from_lower(h);
            if (l == 0) up = half ? seam[0][dl][0] : 0.f;
            float dn = dpp_from_upper(h);
            if (l == 63) dn = half ? 0.f : seam[0][dl][1];
            float X = Xo;
            h = fmaf(sL, X, (nl * up + nm * h + nr * dn) * inv);
            Xo = xpo[xstep2];                     // prefetch t+3 X
            ycol[1][dl][i] = fmaf(h, sU, X * sD);
            if (seam_lo) seam[1][dl][0] = h;
            if (seam_hi) seam[1][dl][1] = h;
        }
        gptr += 4096;
        xpe += xstep2;
        xpo += xstep2;
        __syncthreads();
        if (tid < 128) ypp[128] = ycol[1][0][tid] + ycol[1][1][tid];
        ypp += 256;
    }
}

// ---------------------------------------------------------------------------
// K5a: merge partials (ym = ypA+ypB) + per-pixel LN stats (mu, rstd).
__global__ __launch_bounds__(256) void k5a_stats(const float* __restrict__ ypA,
                                                 const float* __restrict__ ypB,
                                                 float* __restrict__ ym,
                                                 float* __restrict__ mu,
                                                 float* __restrict__ rstd) {
    __shared__ float s_sum[8][32];
    __shared__ float s_ssq[8][32];
    int blk = blockIdx.x;
    int b = blk >> 9;
    int px0 = (blk & 511) * 32;
    int tid = threadIdx.x;
    int pl = tid & 31, cg = tid >> 5;
    int c0 = cg * 24;
    size_t base = ((size_t)b * CI + c0) * NPIX + px0 + pl;
    const float* pa = ypA + base;
    const float* pb = ypB + base;
    float* pm = ym + base;
    float va[24], vb[24];
#pragma unroll
    for (int j = 0; j < 24; j++) va[j] = pa[(size_t)j * NPIX];
#pragma unroll
    for (int j = 0; j < 24; j++) vb[j] = pb[(size_t)j * NPIX];
    float sum = 0.f, ssq = 0.f;
#pragma unroll
    for (int j = 0; j < 24; j++) {
        float v = va[j] + vb[j];
        pm[(size_t)j * NPIX] = v;
        sum += v;
        ssq = fmaf(v, v, ssq);
    }
    s_sum[cg][pl] = sum; s_ssq[cg][pl] = ssq;
    __syncthreads();
    if (tid < 32) {
        float s = 0.f, qq = 0.f;
#pragma unroll
        for (int g = 0; g < 8; g++) { s += s_sum[g][tid]; qq += s_ssq[g][tid]; }
        float m = s * (1.f / 192.f);
        float var = qq * (1.f / 192.f) - m * m;
        mu[(size_t)b * NPIX + px0 + tid] = m;
        rstd[(size_t)b * NPIX + px0 + tid] = rsqrtf(var + 1e-5f);
    }
}

// ---------------------------------------------------------------------------
// K5b: per-(b,c) ssq of NORMALIZED values (no yt write — k6 re-derives).
__global__ __launch_bounds__(256) void k5b_norm(const float* __restrict__ ym,
                                                const float* __restrict__ mu,
                                                const float* __restrict__ rstd,
                                                const float* __restrict__ ln_w,
                                                const float* __restrict__ ln_b,
                                                float* __restrict__ gxs) {
    __shared__ float red[4];
    int blk = blockIdx.x;
    int ph = blk & 1;
    int bc = blk >> 1;
    int c = bc % CI;
    int b = bc / CI;
    const float* ymp = ym + (size_t)bc * NPIX;
    const float* mup = mu + (size_t)b * NPIX;
    const float* rsp = rstd + (size_t)b * NPIX;
    int tid = threadIdx.x;
    float lw = ln_w[c], lb = ln_b[c];
    float acc = 0.f;
#pragma unroll
    for (int it = 0; it < 8; it++) {
        int p = ph * 8192 + it * 1024 + tid * 4;
        float4 v = *(const float4*)&ymp[p];
        float4 m = *(const float4*)&mup[p];
        float4 r = *(const float4*)&rsp[p];
        float vn0 = (v.x - m.x) * r.x * lw + lb;
        float vn1 = (v.y - m.y) * r.y * lw + lb;
        float vn2 = (v.z - m.z) * r.z * lw + lb;
        float vn3 = (v.w - m.w) * r.w * lw + lb;
        acc += vn0 * vn0 + vn1 * vn1 + vn2 * vn2 + vn3 * vn3;
    }
#pragma unroll
    for (int m = 1; m < 64; m <<= 1) acc += __shfl_xor(acc, m);
    if ((tid & 63) == 0) red[tid >> 6] = acc;
    __syncthreads();
    if (tid == 0) {
        atomicAdd(&gxs[bc], red[0] + red[1] + red[2] + red[3]);
    }
}

// ---------------------------------------------------------------------------
// K6: LN+GRN folded to per-channel affine on (ym,mu,rstd) + out-proj conv1x1
// + transpose store to NCHW.
__global__ __launch_bounds__(256) void k6_out(
        const float* __restrict__ ym, const float* __restrict__ mu,
        const float* __restrict__ rstd, const float* __restrict__ gxs,
        const float* __restrict__ grn_gamma, const float* __restrict__ grn_beta,
        const float* __restrict__ ln_w, const float* __restrict__ ln_b,
        const float* __restrict__ w_out, float* __restrict__ outp) {
    __shared__ float scale_s[CI];   // A_c
    __shared__ float beta_s[CI];    // B_c
    __shared__ float redv[1];
    __shared__ float stage[96 * 16 * 8];
    int blk = blockIdx.x;
    int b = blk >> 7;
    int rest = blk & 127;
    int i0 = (rest >> 4) * 16;
    int t0 = (rest & 15) * 8;
    int tid = threadIdx.x;
    if (tid < CI) scale_s[tid] = sqrtf(gxs[b * CI + tid]);
    __syncthreads();
    if (tid < 64) {
        float p = scale_s[tid] + scale_s[tid + 64] + scale_s[tid + 128];
#pragma unroll
        for (int m = 1; m < 64; m <<= 1) p += __shfl_xor(p, m);
        if (tid == 0) redv[0] = p * (1.f / 192.f);
    }
    __syncthreads();
    float mean = redv[0];
    if (tid < CI) {
        float nx = scale_s[tid] / (mean + 1e-6f);
        float sc = 1.f + grn_gamma[tid] * nx;
        scale_s[tid] = ln_w[tid] * sc;
        beta_s[tid] = ln_b[tid] * sc + grn_beta[tid];
    }
    __syncthreads();

    int og = tid >> 6;          // wave-uniform
    int o0 = og * 24;
    int pg = tid & 63;
    int tt = pg >> 3;           // 8 t-cols
    int ii0 = (pg & 7) * 2;     // 16 i-rows, 2 per lane
    float acc[24][2];
#pragma unroll
    for (int j = 0; j < 24; j++) { acc[j][0] = 0.f; acc[j][1] = 0.f; }
    int pbase = (t0 + tt) * 128 + (i0 + ii0);
    const float* ybase = ym + ((size_t)b * CI) * NPIX + pbase;
    float2 mm = *(const float2*)&mu[(size_t)b * NPIX + pbase];
    float2 rr = *(const float2*)&rstd[(size_t)b * NPIX + pbase];
#pragma unroll 2
    for (int cc = 0; cc < CI; cc++) {
        float2 yv = *(const float2*)&ybase[(size_t)cc * NPIX];
        float A = scale_s[cc], Bc = beta_s[cc];
        float y0 = fmaf((yv.x - mm.x) * rr.x, A, Bc);
        float y1 = fmaf((yv.y - mm.y) * rr.y, A, Bc);
#pragma unroll
        for (int j = 0; j < 24; j++) {
            float wv = w_out[(size_t)(o0 + j) * CI + cc];
            acc[j][0] += wv * y0; acc[j][1] += wv * y1;
        }
    }
#pragma unroll
    for (int j = 0; j < 24; j++) {
        stage[((o0 + j) * 16 + ii0 + 0) * 8 + tt] = acc[j][0];
        stage[((o0 + j) * 16 + ii0 + 1) * 8 + tt] = acc[j][1];
    }
    __syncthreads();
    for (int k = 0; k < 48; k++) {
        int L = k * 256 + tid;
        int o = L >> 7;
        int r = L & 127;
        int ii = r >> 3, t2 = r & 7;
        outp[((size_t)(b * CM + o)) * NPIX + (i0 + ii) * 128 + (t0 + t2)] = stage[L];
    }
}

// ---------------------------------------------------------------------------
extern "C" void kernel_launch(void* const* d_in, const int* in_sizes, int n_in,
                              void* d_out, int out_size, void* d_ws, size_t ws_size,
                              hipStream_t stream) {
    const float* x        = (const float*)d_in[0];
    const float* w_in     = (const float*)d_in[1];
    const float* w_dw     = (const float*)d_in[2];
    const float* b_dw     = (const float*)d_in[3];
    const float* w_xdown  = (const float*)d_in[4];
    const float* w_wup    = (const float*)d_in[5];
    const float* w_lup    = (const float*)d_in[6];
    const float* w_uup    = (const float*)d_in[7];
    const float* w_ddown  = (const float*)d_in[8];
    const float* w_m      = (const float*)d_in[9];
    const float* grn_gamma= (const float*)d_in[10];
    const float* grn_beta = (const float*)d_in[11];
    const float* ln_w     = (const float*)d_in[12];
    const float* ln_b     = (const float*)d_in[13];
    const float* w_out    = (const float*)d_in[14];
    float* ws    = (float*)d_ws;
    float* x1pre = ws + OFF_X1PRE;
    float* x1    = ws + OFF_X1;
    float* x1T   = ws + OFF_X1T;
    float* xp    = ws + OFF_XP;
    float* ypA   = ws + OFF_YPA;
    float* ypB   = ws + OFF_YPB;
    float* ym    = ws + OFF_YM;
    float* mu    = ws + OFF_MU;
    float* rstd  = ws + OFF_RSTD;
    float* gxs   = ws + OFF_GXS;
    float* outp  = (float*)d_out;

    hipMemsetAsync(gxs, 0, BB * CI * sizeof(float), stream);
    dim3 g1(256, 3);
    k1_conv_in<<<g1, 256, 0, stream>>>(x, w_in, x1pre);
    k2_dwconv<<<BB * CI * 4, 256, 0, stream>>>(x1pre, w_dw, b_dw, x1, x1T);
    k3_xp<<<BB * 128 * 4, 256, 0, stream>>>(x1T, w_xdown, xp);
    k4_scan<<<BB * CI * 2, 256, 0, stream>>>(x1, x1T, xp, w_wup, w_lup, w_uup,
                                             w_ddown, w_m, ypA, ypB);
    k5a_stats<<<BB * 512, 256, 0, stream>>>(ypA, ypB, ym, mu, rstd);
    k5b_norm<<<BB * CI * 2, 256, 0, stream>>>(ym, mu, rstd, ln_w, ln_b, gxs);
    k6_out<<<256, 256, 0, stream>>>(ym, mu, rstd, gxs, grn_gamma, grn_beta,
                                    ln_w, ln_b, w_out, outp);
}

// Round 13
// 261.811 us; speedup vs baseline: 1.3035x; 1.0023x over previous
//
#include <hip/hip_runtime.h>

typedef float v2f __attribute__((ext_vector_type(2)));

// Problem constants
constexpr int BB = 2;        // batch
constexpr int CM = 96;       // d_model
constexpr int CI = 192;      // d_inner
constexpr int NPIX = 128 * 128;   // 16384
constexpr int DS = 16;            // d_state
constexpr int DC = 4 * CI;        // 768

// workspace layout (floats). Overlays:
//   ypB <- x1pre (dead after K2);  ym <- x1T (dead after K4);
//   mu/rstd <- xp (dead after K4).
constexpr size_t OFF_X1PRE = 0;
constexpr size_t OFF_X1    = 6291456;
constexpr size_t OFF_X1T   = 12582912;
constexpr size_t OFF_XP    = 18874368;
constexpr size_t OFF_YPA   = 19398656;
constexpr size_t OFF_YPB   = 0;          // alias x1pre
constexpr size_t OFF_YM    = 12582912;   // alias x1T
constexpr size_t OFF_MU    = 18874368;   // alias xp (first 32768)
constexpr size_t OFF_RSTD  = 18874368 + 32768;
constexpr size_t OFF_GXS   = 25690112;

__device__ __forceinline__ float frcp(float x) { return __builtin_amdgcn_rcpf(x); }
// DPP whole-wave shifts: from_lower = lane n reads lane n-1 (lane0 -> 0),
// from_upper = lane n reads lane n+1 (lane63 -> 0).
__device__ __forceinline__ float dpp_from_lower(float x) {
    return __int_as_float(__builtin_amdgcn_update_dpp(
        0, __float_as_int(x), 0x138, 0xf, 0xf, false));   // wave_shr1
}
__device__ __forceinline__ float dpp_from_upper(float x) {
    return __int_as_float(__builtin_amdgcn_update_dpp(
        0, __float_as_int(x), 0x130, 0xf, 0xf, false));   // wave_shl1
}

// ---------------------------------------------------------------------------
// K1: x1_pre = conv1x1(x, w_in)   (B,96,H,W) -> (B,192,H,W)
__global__ __launch_bounds__(256) void k1_conv_in(const float* __restrict__ x,
                                                  const float* __restrict__ w_in,
                                                  float* __restrict__ x1pre) {
    __shared__ float xs[16][128];
    __shared__ float wsh[16][64];
    int pt = blockIdx.x;
    int b = pt >> 7;
    int pxb = (pt & 127) * 128;
    int cb = blockIdx.y * 64;
    int tid = threadIdx.x;
    int cl0 = (tid >> 5) * 8;
    int px0 = (tid & 31) * 4;
    float acc[8][4];
#pragma unroll
    for (int i = 0; i < 8; i++)
#pragma unroll
        for (int j = 0; j < 4; j++) acc[i][j] = 0.f;

    for (int m0 = 0; m0 < 96; m0 += 16) {
        {
            int e = tid * 8;
            int ml = e >> 7, pp = e & 127;
            const float* src = &x[((size_t)(b * CM + m0 + ml)) * NPIX + pxb + pp];
            *(float4*)&xs[ml][pp] = *(const float4*)(src);
            *(float4*)&xs[ml][pp + 4] = *(const float4*)(src + 4);
        }
        {
            int cl = tid >> 2, mq = (tid & 3) * 4;
            float4 v = *(const float4*)&w_in[(size_t)(cb + cl) * CM + m0 + mq];
            wsh[mq + 0][cl] = v.x; wsh[mq + 1][cl] = v.y;
            wsh[mq + 2][cl] = v.z; wsh[mq + 3][cl] = v.w;
        }
        __syncthreads();
#pragma unroll
        for (int m = 0; m < 16; m++) {
            float4 wv0 = *(const float4*)&wsh[m][cl0];
            float4 wv1 = *(const float4*)&wsh[m][cl0 + 4];
            float4 xv = *(const float4*)&xs[m][px0];
            float wr[8] = {wv0.x, wv0.y, wv0.z, wv0.w, wv1.x, wv1.y, wv1.z, wv1.w};
            float xr[4] = {xv.x, xv.y, xv.z, xv.w};
#pragma unroll
            for (int i = 0; i < 8; i++)
#pragma unroll
                for (int j = 0; j < 4; j++) acc[i][j] = fmaf(wr[i], xr[j], acc[i][j]);
        }
        __syncthreads();
    }
#pragma unroll
    for (int i = 0; i < 8; i++) {
        float4 v = {acc[i][0], acc[i][1], acc[i][2], acc[i][3]};
        *(float4*)&x1pre[((size_t)(b * CI + cb + cl0 + i)) * NPIX + pxb + px0] = v;
    }
}

// ---------------------------------------------------------------------------
// K2: x1 = dwconv3x3(x1_pre)+b, writes BOTH x1 [h][w] and x1T [w][h].
__global__ __launch_bounds__(256) void k2_dwconv(const float* __restrict__ x1pre,
                                                 const float* __restrict__ w_dw,
                                                 const float* __restrict__ b_dw,
                                                 float* __restrict__ x1,
                                                 float* __restrict__ x1T) {
    __shared__ float inT[66][67];
    __shared__ float outT[64][65];
    int blk = blockIdx.x;
    int bc = blk >> 2;
    int tile = blk & 3;
    int h0 = (tile >> 1) * 64, w0 = (tile & 1) * 64;
    int c = bc % CI;
    const float* src = x1pre + (size_t)bc * NPIX;
    int tid = threadIdx.x;
    for (int idx = tid; idx < 66 * 66; idx += 256) {
        int r = idx / 66, cl = idx - r * 66;
        int hh = h0 - 1 + r, ww = w0 - 1 + cl;
        float v = 0.f;
        if ((unsigned)hh < 128u && (unsigned)ww < 128u) v = src[hh * 128 + ww];
        inT[r][cl] = v;
    }
    float w00 = w_dw[c * 9 + 0], w01 = w_dw[c * 9 + 1], w02 = w_dw[c * 9 + 2];
    float w10 = w_dw[c * 9 + 3], w11 = w_dw[c * 9 + 4], w12 = w_dw[c * 9 + 5];
    float w20 = w_dw[c * 9 + 6], w21 = w_dw[c * 9 + 7], w22 = w_dw[c * 9 + 8];
    float bias = b_dw[c];
    __syncthreads();
    int cl = tid & 63, r0 = tid >> 6;
#pragma unroll 4
    for (int k = 0; k < 16; k++) {
        int r = k * 4 + r0;
        float s = w00 * inT[r][cl]     + w01 * inT[r][cl + 1]     + w02 * inT[r][cl + 2]
                + w10 * inT[r + 1][cl] + w11 * inT[r + 1][cl + 1] + w12 * inT[r + 1][cl + 2]
                + w20 * inT[r + 2][cl] + w21 * inT[r + 2][cl + 1] + w22 * inT[r + 2][cl + 2]
                + bias;
        x1[(size_t)bc * NPIX + (h0 + r) * 128 + w0 + cl] = s;
        outT[r][cl] = s;
    }
    __syncthreads();
#pragma unroll 4
    for (int k = 0; k < 16; k++) {
        int r = k * 4 + r0;
        x1T[(size_t)bc * NPIX + (w0 + r) * 128 + h0 + cl] = outT[cl][r];
    }
}

// ---------------------------------------------------------------------------
// K3: xp = conv1x1(x1, w_xdown) via x1T, stored (b, w, h, 16).
__global__ __launch_bounds__(256) void k3_xp(const float* __restrict__ x1T,
                                             const float* __restrict__ w_xdown,
                                             float* __restrict__ xp) {
    __shared__ float wsh_t[CI * DS];        // [c][s] transposed, 12 KB
    __shared__ float red[8][32][20];        // padded, 20.5 KB
    int blk = blockIdx.x;
    int b = blk >> 9;
    int rest = blk & 511;
    int t = rest >> 2;                      // w index
    int hq = rest & 3;
    int tid = threadIdx.x;
#pragma unroll
    for (int rep = 0; rep < 12; rep++) {
        int e = rep * 256 + tid;            // e = s*CI + c
        int s = e / CI;
        int cc = e - s * CI;
        wsh_t[cc * DS + s] = w_xdown[e];
    }
    int pl = tid & 31;                      // px within quarter
    int cg = tid >> 5;                      // 8 groups
    int c0 = cg * 24;
    int hpix = hq * 32 + pl;
    __syncthreads();
    float acc[DS];
#pragma unroll
    for (int s = 0; s < DS; s++) acc[s] = 0.f;
    const float* xb = x1T + ((size_t)b * CI + c0) * NPIX + t * 128 + hpix;
#pragma unroll 4
    for (int cc = 0; cc < 24; cc++) {
        float v = xb[(size_t)cc * NPIX];
        const float4* wr4 = (const float4*)&wsh_t[(c0 + cc) * DS];
        float4 w0 = wr4[0], w1 = wr4[1], w2 = wr4[2], w3 = wr4[3];
        acc[0] = fmaf(w0.x, v, acc[0]);  acc[1] = fmaf(w0.y, v, acc[1]);
        acc[2] = fmaf(w0.z, v, acc[2]);  acc[3] = fmaf(w0.w, v, acc[3]);
        acc[4] = fmaf(w1.x, v, acc[4]);  acc[5] = fmaf(w1.y, v, acc[5]);
        acc[6] = fmaf(w1.z, v, acc[6]);  acc[7] = fmaf(w1.w, v, acc[7]);
        acc[8] = fmaf(w2.x, v, acc[8]);  acc[9] = fmaf(w2.y, v, acc[9]);
        acc[10] = fmaf(w2.z, v, acc[10]); acc[11] = fmaf(w2.w, v, acc[11]);
        acc[12] = fmaf(w3.x, v, acc[12]); acc[13] = fmaf(w3.y, v, acc[13]);
        acc[14] = fmaf(w3.z, v, acc[14]); acc[15] = fmaf(w3.w, v, acc[15]);
    }
#pragma unroll
    for (int q = 0; q < 4; q++)
        *(float4*)&red[cg][pl][q * 4] = *(float4*)&acc[q * 4];
    __syncthreads();
    int px = tid >> 3;
    int s2 = (tid & 7) * 2;
    float r0 = 0.f, r1 = 0.f;
#pragma unroll
    for (int g = 0; g < 8; g++) { r0 += red[g][px][s2]; r1 += red[g][px][s2 + 1]; }
    float2 o2 = {r0, r1};
    *(float2*)&xp[(((size_t)b * 128 + t) * 128 + hq * 32 + px) * DS + s2] = o2;
}

// ---------------------------------------------------------------------------
// K4: fused gate-compute + tridiagonal scan, dir-PAIR per block (round-8
// structure + round-12 DPP wave shifts on the h-recurrence chain).
#define GLOAD(P, ptr) { const v2f* _gp = (const v2f*)(ptr);                  \
    P##0 = _gp[0]; P##1 = _gp[1]; P##2 = _gp[2]; P##3 = _gp[3];              \
    P##4 = _gp[4]; P##5 = _gp[5]; P##6 = _gp[6]; P##7 = _gp[7]; }

#define DACC(j, P) { aGl += wGl[j] * P; aGm += wGm[j] * P; aGr += wGr[j] * P; \
    aL += wL[j] * P; aU += wU[j] * P; aD += wD[j] * P; }

__global__ __launch_bounds__(256, 3) void k4_scan(
        const float* __restrict__ x1, const float* __restrict__ x1T,
        const float* __restrict__ xp,
        const float* __restrict__ w_wup, const float* __restrict__ w_lup,
        const float* __restrict__ w_uup, const float* __restrict__ w_ddown,
        const float* __restrict__ w_m,
        float* __restrict__ ypA, float* __restrict__ ypB) {
    __shared__ float ycol[2][2][128];
    __shared__ float seam[2][2][2];
    int blk = blockIdx.x;
    int parity = blk & 1;
    int bc = blk >> 1;
    int c = bc % CI;
    int b = bc / CI;
    int tid = threadIdx.x;
    int dl = tid >> 7;
    int half = (tid >> 6) & 1;
    int l = tid & 63;
    int i = half * 64 + l;
    int dir = __builtin_amdgcn_readfirstlane(parity + 2 * dl);
    const float* xsrc = (parity ? x1 : x1T) + (size_t)bc * NPIX;
    float* yp = (parity ? ypB : ypA) + (size_t)bc * NPIX;

    int q = dir * CI + c;
    float wm = w_m[dir];
    v2f wGl[8], wGm[8], wGr[8], wL[8], wU[8], wD[8];
#pragma unroll
    for (int j = 0; j < 8; j++) {
        float2 a;
        a = *(const float2*)&w_wup[(size_t)q * DS + 2 * j];            wGl[j] = v2f{a.x, a.y};
        a = *(const float2*)&w_wup[(size_t)(DC + q) * DS + 2 * j];     wGm[j] = v2f{a.x, a.y};
        a = *(const float2*)&w_wup[(size_t)(2 * DC + q) * DS + 2 * j]; wGr[j] = v2f{a.x, a.y};
        a = *(const float2*)&w_lup[(size_t)q * DS + 2 * j];            wL[j]  = v2f{a.x, a.y};
        a = *(const float2*)&w_uup[(size_t)q * DS + 2 * j];            wU[j]  = v2f{a.x * wm, a.y * wm};
        a = *(const float2*)&w_ddown[(size_t)q * DS + 2 * j];          wD[j]  = v2f{a.x * wm, a.y * wm};
    }
    if (tid < 8) ((float*)seam)[tid] = 0.f;
    __syncthreads();

    bool at_top = (i == 0), at_bot = (i == 127);
    bool seam_lo = (half == 0 && l == 63);
    bool seam_hi = (half == 1 && l == 0);

    const float* gbase = xp + ((size_t)b * NPIX + i) * DS;
    const float* gptr = gbase + 4096;                  // points at t+2 rows
    int xstep = dl ? -128 : 128;
    int xstep2 = 2 * xstep;
    const float* xpe = xsrc + (dl ? 127 * 128 : 0) + i;   // even-step X
    const float* xpo = xpe + xstep;                       // odd-step X
    float* ypp = yp + (tid & 127);

    v2f e0, e1, e2, e3, e4, e5, e6, e7;
    v2f o0, o1, o2, o3, o4, o5, o6, o7;
    GLOAD(e, gbase);
    GLOAD(o, gbase + 2048);
    float Xe = xpe[0];
    float Xo = xpo[0];

    float h = 0.f;
    for (int t = 0; t < 128; t += 2) {
        // ---- even step: buf 0, prev seam = seam[1] ----
        {
            v2f aGl = wGl[0] * e0, aGm = wGm[0] * e0, aGr = wGr[0] * e0;
            v2f aL = wL[0] * e0, aU = wU[0] * e0, aD = wD[0] * e0;
            DACC(1, e1) DACC(2, e2) DACC(3, e3) DACC(4, e4)
            DACC(5, e5) DACC(6, e6) DACC(7, e7)
            GLOAD(e, gptr);                       // prefetch t+2 (past-end safe)
            float sGl = aGl.x + aGl.y, sGm = aGm.x + aGm.y, sGr = aGr.x + aGr.y;
            float sL = aL.x + aL.y, sU = aU.x + aU.y, sD = aD.x + aD.y;
            float el = __expf(fminf(-sGl, 40.f));
            float em = __expf(fminf(-sGm, 40.f));
            float er = __expf(fminf(-sGr, 40.f));
            float tl = 1.f + el, tm = 1.f + em, tr = 1.f + er;
            float nl = at_top ? 0.f : tm * tr;
            float nm = tl * tr;
            float nr = at_bot ? 0.f : tl * tm;
            float inv = frcp(nl + nm + nr);
            float up = dpp_from_lower(h);
            if (l == 0) up = half ? seam[1][dl][0] : 0.f;
            float dn = dpp_from_upper(h);
            if (l == 63) dn = half ? 0.f : seam[1][dl][1];
            float X = Xe;
            h = fmaf(sL, X, (nl * up + nm * h + nr * dn) * inv);
            Xe = xpe[xstep2];                     // prefetch t+2 X (past-end safe)
            ycol[0][dl][i] = fmaf(h, sU, X * sD);
            if (seam_lo) seam[0][dl][0] = h;
            if (seam_hi) seam[0][dl][1] = h;
        }
        __syncthreads();
        if (tid < 128) ypp[0] = ycol[0][0][tid] + ycol[0][1][tid];
        // ---- odd step: buf 1, prev seam = seam[0] ----
        {
            v2f aGl = wGl[0] * o0, aGm = wGm[0] * o0, aGr = wGr[0] * o0;
            v2f aL = wL[0] * o0, aU = wU[0] * o0, aD = wD[0] * o0;
            DACC(1, o1) DACC(2, o2) DACC(3, o3) DACC(4, o4)
            DACC(5, o5) DACC(6, o6) DACC(7, o7)
            GLOAD(o, gptr + 2048);                // prefetch t+3
            float sGl = aGl.x + aGl.y, sGm = aGm.x + aGm.y, sGr = aGr.x + aGr.y;
            float sL = aL.x + aL.y, sU = aU.x + aU.y, sD = aD.x + aD.y;
            float el = __expf(fminf(-sGl, 40.f));
            float em = __expf(fminf(-sGm, 40.f));
            float er = __expf(fminf(-sGr, 40.f));
            float tl = 1.f + el, tm = 1.f + em, tr = 1.f + er;
            float nl = at_top ? 0.f : tm * tr;
            float nm = tl * tr;
            float nr = at_bot ? 0.f : tl * tm;
            float inv = frcp(nl + nm + nr);
            float up = dpp_from_lower(h);
            if (l == 0) up = half ? seam[0][dl][0] : 0.f;
            float dn = dpp_from_upper(h);
            if (l == 63) dn = half ? 0.f : seam[0][dl][1];
            float X = Xo;
            h = fmaf(sL, X, (nl * up + nm * h + nr * dn) * inv);
            Xo = xpo[xstep2];                     // prefetch t+3 X
            ycol[1][dl][i] = fmaf(h, sU, X * sD);
            if (seam_lo) seam[1][dl][0] = h;
            if (seam_hi) seam[1][dl][1] = h;
        }
        gptr += 4096;
        xpe += xstep2;
        xpo += xstep2;
        __syncthreads();
        if (tid < 128) ypp[128] = ycol[1][0][tid] + ycol[1][1][tid];
        ypp += 256;
    }
}

// ---------------------------------------------------------------------------
// K5a: merge partials (ym = ypA+ypB) + per-pixel LN stats (mu, rstd).
__global__ __launch_bounds__(256) void k5a_stats(const float* __restrict__ ypA,
                                                 const float* __restrict__ ypB,
                                                 float* __restrict__ ym,
                                                 float* __restrict__ mu,
                                                 float* __restrict__ rstd) {
    __shared__ float s_sum[8][32];
    __shared__ float s_ssq[8][32];
    int blk = blockIdx.x;
    int b = blk >> 9;
    int px0 = (blk & 511) * 32;
    int tid = threadIdx.x;
    int pl = tid & 31, cg = tid >> 5;
    int c0 = cg * 24;
    size_t base = ((size_t)b * CI + c0) * NPIX + px0 + pl;
    const float* pa = ypA + base;
    const float* pb = ypB + base;
    float* pm = ym + base;
    float va[24], vb[24];
#pragma unroll
    for (int j = 0; j < 24; j++) va[j] = pa[(size_t)j * NPIX];
#pragma unroll
    for (int j = 0; j < 24; j++) vb[j] = pb[(size_t)j * NPIX];
    float sum = 0.f, ssq = 0.f;
#pragma unroll
    for (int j = 0; j < 24; j++) {
        float v = va[j] + vb[j];
        pm[(size_t)j * NPIX] = v;
        sum += v;
        ssq = fmaf(v, v, ssq);
    }
    s_sum[cg][pl] = sum; s_ssq[cg][pl] = ssq;
    __syncthreads();
    if (tid < 32) {
        float s = 0.f, qq = 0.f;
#pragma unroll
        for (int g = 0; g < 8; g++) { s += s_sum[g][tid]; qq += s_ssq[g][tid]; }
        float m = s * (1.f / 192.f);
        float var = qq * (1.f / 192.f) - m * m;
        mu[(size_t)b * NPIX + px0 + tid] = m;
        rstd[(size_t)b * NPIX + px0 + tid] = rsqrtf(var + 1e-5f);
    }
}

// ---------------------------------------------------------------------------
// K5b: per-(b,c) ssq of NORMALIZED values. One block per (b,c); plain store
// (no atomic, no memset dependency).
__global__ __launch_bounds__(256) void k5b_norm(const float* __restrict__ ym,
                                                const float* __restrict__ mu,
                                                const float* __restrict__ rstd,
                                                const float* __restrict__ ln_w,
                                                const float* __restrict__ ln_b,
                                                float* __restrict__ gxs) {
    __shared__ float red[4];
    int bc = blockIdx.x;               // b*CI + c
    int c = bc % CI;
    int b = bc / CI;
    const float* ymp = ym + (size_t)bc * NPIX;
    const float* mup = mu + (size_t)b * NPIX;
    const float* rsp = rstd + (size_t)b * NPIX;
    int tid = threadIdx.x;
    float lw = ln_w[c], lb = ln_b[c];
    float acc = 0.f;
#pragma unroll
    for (int it = 0; it < 16; it++) {
        int p = it * 1024 + tid * 4;
        float4 v = *(const float4*)&ymp[p];
        float4 m = *(const float4*)&mup[p];
        float4 r = *(const float4*)&rsp[p];
        float vn0 = (v.x - m.x) * r.x * lw + lb;
        float vn1 = (v.y - m.y) * r.y * lw + lb;
        float vn2 = (v.z - m.z) * r.z * lw + lb;
        float vn3 = (v.w - m.w) * r.w * lw + lb;
        acc += vn0 * vn0 + vn1 * vn1 + vn2 * vn2 + vn3 * vn3;
    }
#pragma unroll
    for (int m = 1; m < 64; m <<= 1) acc += __shfl_xor(acc, m);
    if ((tid & 63) == 0) red[tid >> 6] = acc;
    __syncthreads();
    if (tid == 0) {
        gxs[bc] = red[0] + red[1] + red[2] + red[3];
    }
}

// ---------------------------------------------------------------------------
// K6: LN+GRN folded to per-channel affine on (ym,mu,rstd) + out-proj conv1x1
// + transpose store to NCHW. r13: 512 threads, 8 o-groups of 12 ->
// 2 waves/SIMD for latency cover (same tile/addressing as proven version).
__global__ __launch_bounds__(512) void k6_out(
        const float* __restrict__ ym, const float* __restrict__ mu,
        const float* __restrict__ rstd, const float* __restrict__ gxs,
        const float* __restrict__ grn_gamma, const float* __restrict__ grn_beta,
        const float* __restrict__ ln_w, const float* __restrict__ ln_b,
        const float* __restrict__ w_out, float* __restrict__ outp) {
    __shared__ float scale_s[CI];   // A_c
    __shared__ float beta_s[CI];    // B_c
    __shared__ float redv[1];
    __shared__ float stage[96 * 16 * 8];
    int blk = blockIdx.x;
    int b = blk >> 7;
    int rest = blk & 127;
    int i0 = (rest >> 4) * 16;
    int t0 = (rest & 15) * 8;
    int tid = threadIdx.x;
    if (tid < CI) scale_s[tid] = sqrtf(gxs[b * CI + tid]);
    __syncthreads();
    if (tid < 64) {
        float p = scale_s[tid] + scale_s[tid + 64] + scale_s[tid + 128];
#pragma unroll
        for (int m = 1; m < 64; m <<= 1) p += __shfl_xor(p, m);
        if (tid == 0) redv[0] = p * (1.f / 192.f);
    }
    __syncthreads();
    float mean = redv[0];
    if (tid < CI) {
        float nx = scale_s[tid] / (mean + 1e-6f);
        float sc = 1.f + grn_gamma[tid] * nx;
        scale_s[tid] = ln_w[tid] * sc;
        beta_s[tid] = ln_b[tid] * sc + grn_beta[tid];
    }
    __syncthreads();

    int og = tid >> 6;          // wave-uniform, 0..7
    int o0 = og * 12;
    int pg = tid & 63;
    int tt = pg >> 3;           // 8 t-cols
    int ii0 = (pg & 7) * 2;     // 16 i-rows, 2 per lane
    float acc[12][2];
#pragma unroll
    for (int j = 0; j < 12; j++) { acc[j][0] = 0.f; acc[j][1] = 0.f; }
    int pbase = (t0 + tt) * 128 + (i0 + ii0);
    const float* ybase = ym + ((size_t)b * CI) * NPIX + pbase;
    float2 mm = *(const float2*)&mu[(size_t)b * NPIX + pbase];
    float2 rr = *(const float2*)&rstd[(size_t)b * NPIX + pbase];
#pragma unroll 2
    for (int cc = 0; cc < CI; cc++) {
        float2 yv = *(const float2*)&ybase[(size_t)cc * NPIX];
        float A = scale_s[cc], Bc = beta_s[cc];
        float y0 = fmaf((yv.x - mm.x) * rr.x, A, Bc);
        float y1 = fmaf((yv.y - mm.y) * rr.y, A, Bc);
#pragma unroll
        for (int j = 0; j < 12; j++) {
            float wv = w_out[(size_t)(o0 + j) * CI + cc];
            acc[j][0] += wv * y0; acc[j][1] += wv * y1;
        }
    }
#pragma unroll
    for (int j = 0; j < 12; j++) {
        stage[((o0 + j) * 16 + ii0 + 0) * 8 + tt] = acc[j][0];
        stage[((o0 + j) * 16 + ii0 + 1) * 8 + tt] = acc[j][1];
    }
    __syncthreads();
    for (int k = 0; k < 24; k++) {
        int L = k * 512 + tid;
        int o = L >> 7;
        int r = L & 127;
        int ii = r >> 3, t2 = r & 7;
        outp[((size_t)(b * CM + o)) * NPIX + (i0 + ii) * 128 + (t0 + t2)] = stage[L];
    }
}

// ---------------------------------------------------------------------------
extern "C" void kernel_launch(void* const* d_in, const int* in_sizes, int n_in,
                              void* d_out, int out_size, void* d_ws, size_t ws_size,
                              hipStream_t stream) {
    const float* x        = (const float*)d_in[0];
    const float* w_in     = (const float*)d_in[1];
    const float* w_dw     = (const float*)d_in[2];
    const float* b_dw     = (const float*)d_in[3];
    const float* w_xdown  = (const float*)d_in[4];
    const float* w_wup    = (const float*)d_in[5];
    const float* w_lup    = (const float*)d_in[6];
    const float* w_uup    = (const float*)d_in[7];
    const float* w_ddown  = (const float*)d_in[8];
    const float* w_m      = (const float*)d_in[9];
    const float* grn_gamma= (const float*)d_in[10];
    const float* grn_beta = (const float*)d_in[11];
    const float* ln_w     = (const float*)d_in[12];
    const float* ln_b     = (const float*)d_in[13];
    const float* w_out    = (const float*)d_in[14];
    float* ws    = (float*)d_ws;
    float* x1pre = ws + OFF_X1PRE;
    float* x1    = ws + OFF_X1;
    float* x1T   = ws + OFF_X1T;
    float* xp    = ws + OFF_XP;
    float* ypA   = ws + OFF_YPA;
    float* ypB   = ws + OFF_YPB;
    float* ym    = ws + OFF_YM;
    float* mu    = ws + OFF_MU;
    float* rstd  = ws + OFF_RSTD;
    float* gxs   = ws + OFF_GXS;
    float* outp  = (float*)d_out;

    dim3 g1(256, 3);
    k1_conv_in<<<g1, 256, 0, stream>>>(x, w_in, x1pre);
    k2_dwconv<<<BB * CI * 4, 256, 0, stream>>>(x1pre, w_dw, b_dw, x1, x1T);
    k3_xp<<<BB * 128 * 4, 256, 0, stream>>>(x1T, w_xdown, xp);
    k4_scan<<<BB * CI * 2, 256, 0, stream>>>(x1, x1T, xp, w_wup, w_lup, w_uup,
                                             w_ddown, w_m, ypA, ypB);
    k5a_stats<<<BB * 512, 256, 0, stream>>>(ypA, ypB, ym, mu, rstd);
    k5b_norm<<<BB * CI, 256, 0, stream>>>(ym, mu, rstd, ln_w, ln_b, gxs);
    k6_out<<<256, 512, 0, stream>>>(ym, mu, rstd, gxs, grn_gamma, grn_beta,
                                    ln_w, ln_b, w_out, outp);
}